// Round 5
// baseline (964.119 us; speedup 1.0000x reference)
//
#include <hip/hip_runtime.h>
#include <math.h>

typedef __attribute__((ext_vector_type(4))) float f32x4;
typedef __attribute__((ext_vector_type(2))) float f32x2;
typedef __attribute__((ext_vector_type(8))) __bf16 bf16x8;
typedef __attribute__((ext_vector_type(4))) unsigned short us4;
typedef unsigned long long u64;

__device__ __forceinline__ unsigned short f2bf(float f) {
  unsigned int u = __float_as_uint(f);
  u += 0x7fffu + ((u >> 16) & 1u);            // RNE
  return (unsigned short)(u >> 16);
}
__device__ __forceinline__ float bf2f(unsigned short h) {
  return __uint_as_float(((unsigned int)h) << 16);
}

__device__ __forceinline__ void gload16(const void* g, void* l) {
  __builtin_amdgcn_global_load_lds(
      (__attribute__((address_space(1))) void*)g,
      (__attribute__((address_space(3))) void*)l, 16, 0, 0);
}

// ---------------- fp32 -> bf16 convert (plain) ----------------
__global__ __launch_bounds__(256) void cvt_bf16(const float* __restrict__ in,
                                                unsigned short* __restrict__ out, int n4) {
  int i = blockIdx.x * 256 + threadIdx.x;
  if (i < n4) {
    float4 v = ((const float4*)in)[i];
    us4 o;
    o[0] = f2bf(v.x); o[1] = f2bf(v.y); o[2] = f2bf(v.z); o[3] = f2bf(v.w);
    ((us4*)out)[i] = o;
  }
}

// ---------------- fp32 -> (hi, lo) bf16 split ----------------
__global__ __launch_bounds__(256) void cvt_split(const float* __restrict__ in,
                                                 unsigned short* __restrict__ hi,
                                                 unsigned short* __restrict__ lo, int n4) {
  int i = blockIdx.x * 256 + threadIdx.x;
  if (i < n4) {
    float4 v = ((const float4*)in)[i];
    us4 h, l;
    float vv[4] = {v.x, v.y, v.z, v.w};
#pragma unroll
    for (int j = 0; j < 4; ++j) {
      unsigned short hh = f2bf(vv[j]);
      h[j] = hh;
      l[j] = f2bf(vv[j] - bf2f(hh));
    }
    ((us4*)hi)[i] = h;
    ((us4*)lo)[i] = l;
  }
}

// ---------------- GEMM: C = A * B^T (bf16 in, fp32 acc) ----------------
// SM=2: fp32 row-major store. SM=4: bf16 V2 fragment-major store (N=1024 layout).
template<int SM>
__global__ __launch_bounds__(256) void gemm_bt(const unsigned short* __restrict__ A,
                                               const unsigned short* __restrict__ B,
                                               void* __restrict__ C,
                                               int M, int N, int K) {
  __shared__ __align__(16) unsigned short As[128 * 32];
  __shared__ __align__(16) unsigned short Bs[128 * 32];
  const int tid = threadIdx.x;
  const int w = tid >> 6, l = tid & 63;
  const int wm = w >> 1, wn = w & 1;
  const int lr = l & 15, lg = l >> 4;
  const long m0 = (long)blockIdx.y * 128, n0 = (long)blockIdx.x * 128;

  f32x4 acc[4][4] = {};

  const int c0 = w * 128 + l;
  const int c1 = c0 + 64;
  const unsigned short* gA0 = A + (m0 + (c0 >> 2)) * K + (c0 & 3) * 8;
  const unsigned short* gA1 = A + (m0 + (c1 >> 2)) * K + (c1 & 3) * 8;
  const unsigned short* gB0 = B + (n0 + (c0 >> 2)) * K + (c0 & 3) * 8;
  const unsigned short* gB1 = B + (n0 + (c1 >> 2)) * K + (c1 & 3) * 8;

  for (int kt = 0; kt < K; kt += 32) {
    gload16(gA0 + kt, &As[(w * 128) * 8]);
    gload16(gA1 + kt, &As[(w * 128 + 64) * 8]);
    gload16(gB0 + kt, &Bs[(w * 128) * 8]);
    gload16(gB1 + kt, &Bs[(w * 128 + 64) * 8]);
    __syncthreads();
    bf16x8 af[4], bfr[4];
#pragma unroll
    for (int mi = 0; mi < 4; ++mi)
      af[mi] = *(const bf16x8*)&As[(wm * 64 + mi * 16 + lr) * 32 + lg * 8];
#pragma unroll
    for (int ni = 0; ni < 4; ++ni)
      bfr[ni] = *(const bf16x8*)&Bs[(wn * 64 + ni * 16 + lr) * 32 + lg * 8];
#pragma unroll
    for (int mi = 0; mi < 4; ++mi)
#pragma unroll
      for (int ni = 0; ni < 4; ++ni)
        acc[mi][ni] = __builtin_amdgcn_mfma_f32_16x16x32_bf16(af[mi], bfr[ni], acc[mi][ni], 0, 0, 0);
    __syncthreads();
  }

#pragma unroll
  for (int mi = 0; mi < 4; ++mi)
#pragma unroll
    for (int ni = 0; ni < 4; ++ni)
#pragma unroll
      for (int j = 0; j < 4; ++j) {
        long r = m0 + wm * 64 + mi * 16 + lg * 4 + j;
        long cc = n0 + wn * 64 + ni * 16 + lr;
        float v = acc[mi][ni][j];
        if (SM == 2) {
          ((float*)C)[r * N + cc] = v;
        } else {  // SM==4: V2 fragment-major
          int kvh = (int)(cc >> 7), d = (int)(cc & 127);
          int c = (int)(r >> 4), t = (int)(r & 15);
          long idx = ((long)(kvh * 128 + c) * 8 + (d >> 4)) * 256 + ((t >> 3) * 16 + (d & 15)) * 8 + (t & 7);
          ((unsigned short*)C)[idx] = f2bf(v);
        }
      }
}

// ---------------- fused split GEMM: C = Ah*Bh^T + Al*Bh^T + Ah*Bl^T (fp32 out) ----------------
__global__ __launch_bounds__(256) void gemm_bt3(const unsigned short* __restrict__ Ah,
                                                const unsigned short* __restrict__ Al,
                                                const unsigned short* __restrict__ Bh,
                                                const unsigned short* __restrict__ Bl,
                                                float* __restrict__ C,
                                                int M, int N, int K) {
  __shared__ __align__(16) unsigned short Ash[128 * 32];
  __shared__ __align__(16) unsigned short Asl[128 * 32];
  __shared__ __align__(16) unsigned short Bsh[128 * 32];
  __shared__ __align__(16) unsigned short Bsl[128 * 32];
  const int tid = threadIdx.x;
  const int w = tid >> 6, l = tid & 63;
  const int wm = w >> 1, wn = w & 1;
  const int lr = l & 15, lg = l >> 4;
  const long m0 = (long)blockIdx.y * 128, n0 = (long)blockIdx.x * 128;

  f32x4 acc[4][4] = {};

  const int c0 = w * 128 + l;
  const int c1 = c0 + 64;
  const long oA0 = (m0 + (c0 >> 2)) * K + (c0 & 3) * 8;
  const long oA1 = (m0 + (c1 >> 2)) * K + (c1 & 3) * 8;
  const long oB0 = (n0 + (c0 >> 2)) * K + (c0 & 3) * 8;
  const long oB1 = (n0 + (c1 >> 2)) * K + (c1 & 3) * 8;

  for (int kt = 0; kt < K; kt += 32) {
    gload16(Ah + oA0 + kt, &Ash[(w * 128) * 8]);
    gload16(Ah + oA1 + kt, &Ash[(w * 128 + 64) * 8]);
    gload16(Al + oA0 + kt, &Asl[(w * 128) * 8]);
    gload16(Al + oA1 + kt, &Asl[(w * 128 + 64) * 8]);
    gload16(Bh + oB0 + kt, &Bsh[(w * 128) * 8]);
    gload16(Bh + oB1 + kt, &Bsh[(w * 128 + 64) * 8]);
    gload16(Bl + oB0 + kt, &Bsl[(w * 128) * 8]);
    gload16(Bl + oB1 + kt, &Bsl[(w * 128 + 64) * 8]);
    __syncthreads();
    bf16x8 afh[4], afl[4], bfh[4], bfl[4];
#pragma unroll
    for (int mi = 0; mi < 4; ++mi) {
      afh[mi] = *(const bf16x8*)&Ash[(wm * 64 + mi * 16 + lr) * 32 + lg * 8];
      afl[mi] = *(const bf16x8*)&Asl[(wm * 64 + mi * 16 + lr) * 32 + lg * 8];
    }
#pragma unroll
    for (int ni = 0; ni < 4; ++ni) {
      bfh[ni] = *(const bf16x8*)&Bsh[(wn * 64 + ni * 16 + lr) * 32 + lg * 8];
      bfl[ni] = *(const bf16x8*)&Bsl[(wn * 64 + ni * 16 + lr) * 32 + lg * 8];
    }
#pragma unroll
    for (int mi = 0; mi < 4; ++mi)
#pragma unroll
      for (int ni = 0; ni < 4; ++ni) {
        acc[mi][ni] = __builtin_amdgcn_mfma_f32_16x16x32_bf16(afh[mi], bfh[ni], acc[mi][ni], 0, 0, 0);
        acc[mi][ni] = __builtin_amdgcn_mfma_f32_16x16x32_bf16(afl[mi], bfh[ni], acc[mi][ni], 0, 0, 0);
        acc[mi][ni] = __builtin_amdgcn_mfma_f32_16x16x32_bf16(afh[mi], bfl[ni], acc[mi][ni], 0, 0, 0);
      }
    __syncthreads();
  }

#pragma unroll
  for (int mi = 0; mi < 4; ++mi)
#pragma unroll
    for (int ni = 0; ni < 4; ++ni)
#pragma unroll
      for (int j = 0; j < 4; ++j) {
        long r = m0 + wm * 64 + mi * 16 + lg * 4 + j;
        long cc = n0 + wn * 64 + ni * 16 + lr;
        C[r * N + cc] = acc[mi][ni][j];
      }
}

// ---------------- K2 fragment-major index: K element (s, kvh, d) ----------------
__device__ __forceinline__ long k2idx(int kvh, int s, int d) {
  int ct = s >> 4;
  int lane = (((d & 31) >> 3) << 4) | (s & 15);
  return ((long)(kvh * 128 + ct) * 4 + (d >> 5)) * 512 + lane * 8 + (d & 7);
}

// ---------------- RoPE angle table ----------------
__global__ __launch_bounds__(256) void rope_table(float* __restrict__ ctab,
                                                  float* __restrict__ stab) {
  int idx = blockIdx.x * 256 + threadIdx.x;   // 2048*64
  if (idx >= 2048 * 64) return;
  int s = idx >> 6, d = idx & 63;
  float inv = powf(10000.0f, -(float)d * (1.0f / 64.0f));
  float ang = (float)s * inv;
  ctab[idx] = cosf(ang);
  stab[idx] = sinf(ang);
}

// ---------------- RoPE apply: fp32 -> Q (row-major hi/lo, pre-scaled), K (frag-major hi/lo) ----------------
__global__ __launch_bounds__(256) void rope_apply(const float* __restrict__ Qf,
                                                  const float* __restrict__ Kf,
                                                  const float* __restrict__ ctab,
                                                  const float* __restrict__ stab,
                                                  unsigned short* __restrict__ Qh,
                                                  unsigned short* __restrict__ Ql,
                                                  unsigned short* __restrict__ K2h,
                                                  unsigned short* __restrict__ K2l) {
  int t = blockIdx.x * 256 + threadIdx.x;     // 2048*40*16
  if (t >= 2048 * 40 * 16) return;
  int s = t / 640;
  int rem = t - s * 640;
  int hd = rem >> 4;
  int d4 = (rem & 15) * 4;
  float4 cv = *(const float4*)&ctab[s * 64 + d4];
  float4 sv = *(const float4*)&stab[s * 64 + d4];
  float cc[4] = {cv.x, cv.y, cv.z, cv.w};
  float ss[4] = {sv.x, sv.y, sv.z, sv.w};
  us4 h1, l1, h2, l2;
  if (hd < 32) {
    long row = (long)s * 4096 + hd * 128;
    float4 u1 = *(const float4*)&Qf[row + d4];
    float4 u2 = *(const float4*)&Qf[row + 64 + d4];
    float a1[4] = {u1.x, u1.y, u1.z, u1.w};
    float a2[4] = {u2.x, u2.y, u2.z, u2.w};
    const float scale = 0.08838834764831845f;  // 1/sqrt(128)
#pragma unroll
    for (int j = 0; j < 4; ++j) {
      float y1 = (a1[j] * cc[j] - a2[j] * ss[j]) * scale;
      float y2 = (a2[j] * cc[j] + a1[j] * ss[j]) * scale;
      h1[j] = f2bf(y1); l1[j] = f2bf(y1 - bf2f(h1[j]));
      h2[j] = f2bf(y2); l2[j] = f2bf(y2 - bf2f(h2[j]));
    }
    *(us4*)&Qh[row + d4] = h1;      *(us4*)&Ql[row + d4] = l1;
    *(us4*)&Qh[row + 64 + d4] = h2; *(us4*)&Ql[row + 64 + d4] = l2;
  } else {
    int kvh = hd - 32;
    long row = (long)s * 1024 + kvh * 128;
    float4 u1 = *(const float4*)&Kf[row + d4];
    float4 u2 = *(const float4*)&Kf[row + 64 + d4];
    float a1[4] = {u1.x, u1.y, u1.z, u1.w};
    float a2[4] = {u2.x, u2.y, u2.z, u2.w};
#pragma unroll
    for (int j = 0; j < 4; ++j) {
      float y1 = a1[j] * cc[j] - a2[j] * ss[j];
      float y2 = a2[j] * cc[j] + a1[j] * ss[j];
      h1[j] = f2bf(y1); l1[j] = f2bf(y1 - bf2f(h1[j]));
      h2[j] = f2bf(y2); l2[j] = f2bf(y2 - bf2f(h2[j]));
    }
    long i1 = k2idx(kvh, s, d4);
    long i2 = k2idx(kvh, s, d4 + 64);
    *(us4*)&K2h[i1] = h1; *(us4*)&K2l[i1] = l1;
    *(us4*)&K2h[i2] = h2; *(us4*)&K2l[i2] = l2;
  }
}

// ======== K1: cmax GEMM. block = (q-panel of 128 rows, head); 4 waves x 32 rows. ========
// Writes exact fp32 chunk maxes, chunk-major: cmaxg[(h*128+ct)*2048 + q].
__global__ __launch_bounds__(256, 2) void cmax_gemm(const unsigned short* __restrict__ Qh,
                                                    const unsigned short* __restrict__ Ql,
                                                    const unsigned short* __restrict__ K2h,
                                                    const unsigned short* __restrict__ K2l,
                                                    float* __restrict__ cmaxg) {
  __shared__ __align__(16) unsigned short Ksh[2][8192];  // 64-tok K panel hi (16 KB) x2
  __shared__ __align__(16) unsigned short Ksl[2][8192];  // lo
  const int qp = 15 - (int)blockIdx.x;                   // heavy panels first
  const int h = blockIdx.y;
  const int kvh = h >> 2;
  const int q0 = qp * 128;
  const int tid = threadIdx.x;
  const int w = tid >> 6, l = tid & 63;
  const int lr = l & 15, lg = l >> 4;
  const int npan = 2 * (qp + 1);
  const float NEGINF = -__builtin_inff();

  // Q B-frags in registers: wave w rows q0 + w*32 + rg*16 + lr
  bf16x8 qfh[2][4], qfl[2][4];
#pragma unroll
  for (int rg = 0; rg < 2; ++rg) {
    const unsigned short* qph = Qh + (long)(q0 + w * 32 + rg * 16 + lr) * 4096 + h * 128 + lg * 8;
    const unsigned short* qpl = Ql + (long)(q0 + w * 32 + rg * 16 + lr) * 4096 + h * 128 + lg * 8;
#pragma unroll
    for (int ks = 0; ks < 4; ++ks) {
      qfh[rg][ks] = *(const bf16x8*)(qph + ks * 32);
      qfl[rg][ks] = *(const bf16x8*)(qpl + ks * 32);
    }
  }

  const unsigned short* kbh = K2h + (long)kvh * 128 * 2048;
  const unsigned short* kbl = K2l + (long)kvh * 128 * 2048;

  // stage one 64-token panel (4 ct tiles, contiguous 16 KB each of hi/lo)
#define STAGE(kp, b)                                                     \
  {                                                                      \
    long off = (long)(kp) * 8192;                                        \
    _Pragma("unroll")                                                    \
    for (int i = 0; i < 4; ++i) {                                        \
      int ch = w * 256 + i * 64 + l;                                     \
      gload16(kbh + off + ch * 8, &Ksh[b][ch * 8]);                      \
      gload16(kbl + off + ch * 8, &Ksl[b][ch * 8]);                      \
    }                                                                    \
  }

  STAGE(0, 0);
  __syncthreads();

  for (int kp = 0; kp < npan; ++kp) {
    const int b = kp & 1;
    if (kp + 1 < npan) STAGE(kp + 1, b ^ 1);
    const int t0 = kp * 64;
#pragma unroll
    for (int ct = 0; ct < 4; ++ct) {
      bf16x8 kh[4], kl2[4];
#pragma unroll
      for (int ks = 0; ks < 4; ++ks) {
        kh[ks]  = *(const bf16x8*)&Ksh[b][(ct * 4 + ks) * 512 + l * 8];
        kl2[ks] = *(const bf16x8*)&Ksl[b][(ct * 4 + ks) * 512 + l * 8];
      }
#pragma unroll
      for (int rg = 0; rg < 2; ++rg) {
        f32x4 acc = {};
#pragma unroll
        for (int ks = 0; ks < 4; ++ks) {
          acc = __builtin_amdgcn_mfma_f32_16x16x32_bf16(kh[ks], qfh[rg][ks], acc, 0, 0, 0);
          acc = __builtin_amdgcn_mfma_f32_16x16x32_bf16(kh[ks], qfl[rg][ks], acc, 0, 0, 0);
          acc = __builtin_amdgcn_mfma_f32_16x16x32_bf16(kl2[ks], qfh[rg][ks], acc, 0, 0, 0);
        }
        const int qrow = q0 + w * 32 + rg * 16 + lr;
        float m;
        if (kp < 2 * qp) {                       // fully-causal panel
          m = fmaxf(fmaxf(acc[0], acc[1]), fmaxf(acc[2], acc[3]));
        } else {                                 // diagonal region
          m = NEGINF;
#pragma unroll
          for (int j = 0; j < 4; ++j) {
            int tok = t0 + ct * 16 + lg * 4 + j;
            if (tok <= qrow) m = fmaxf(m, acc[j]);
          }
        }
        m = fmaxf(m, __shfl_xor(m, 16));
        m = fmaxf(m, __shfl_xor(m, 32));
        if (l < 16) cmaxg[(long)(h * 128 + kp * 4 + ct) * 2048 + q0 + w * 32 + rg * 16 + l] = m;
      }
    }
    asm volatile("s_waitcnt vmcnt(0)" ::: "memory");
    __builtin_amdgcn_sched_barrier(0);
    __builtin_amdgcn_s_barrier();
  }
#undef STAGE
}

// ======== K2: per-row top-8 selection. block = (64-row group, head). ========
__global__ __launch_bounds__(256) void select_kernel(const float* __restrict__ cmaxg,
                                                     u64* __restrict__ selEg,
                                                     u64* __restrict__ selOg,
                                                     float* __restrict__ mxg) {
  __shared__ float Lc[128 * 65];                  // [ct][row], padded
  const int r0 = (int)blockIdx.x * 64;
  const int h = blockIdx.y;
  const int tid = threadIdx.x;
  const int w = tid >> 6, l = tid & 63;
  const float NEGINF = -__builtin_inff();

  for (int i = tid; i < 128 * 16; i += 256) {
    int ct = i >> 4, rq = (i & 15) * 4;
    float4 v = *(const float4*)&cmaxg[(long)(h * 128 + ct) * 2048 + r0 + rq];
    Lc[ct * 65 + rq]     = v.x;
    Lc[ct * 65 + rq + 1] = v.y;
    Lc[ct * 65 + rq + 2] = v.z;
    Lc[ct * 65 + rq + 3] = v.w;
  }
  __syncthreads();

  const int c0 = 2 * l, c1 = 2 * l + 1;
#pragma unroll 1
  for (int rs = 0; rs < 16; ++rs) {
    const int rloc = w * 16 + rs;
    const int qr = r0 + rloc;
    const int nctr = (qr >> 4) + 1;
    float v0 = (c0 < nctr) ? Lc[c0 * 65 + rloc] : NEGINF;
    float v1 = (c1 < nctr) ? Lc[c1 * 65 + rloc] : NEGINF;
    const float o0 = v0, o1 = v1;
    float T = NEGINF;
    for (int it = 0; it < 8; ++it) {
      float m = fmaxf(v0, v1);
#pragma unroll
      for (int o = 1; o < 64; o <<= 1) m = fmaxf(m, __shfl_xor(m, o));
      u64 bal = __ballot((v0 == m) || (v1 == m));
      int first = __ffsll(bal) - 1;
      if (l == first) { if (v0 == m) v0 = NEGINF; else v1 = NEGINF; }
      T = m;
    }
    bool okc0 = (c0 < nctr) && ((c0 < 8) || (o0 >= T));
    bool okc1 = (c1 < nctr) && ((c1 < 8) || (o1 >= T));
    u64 bE = __ballot(okc0);
    u64 bO = __ballot(okc1);
    bool al0 = (c0 < nctr) && (okc0 || (c0 * 16 + 15 > qr - 128));
    bool al1 = (c1 < nctr) && (okc1 || (c1 * 16 + 15 > qr - 128));
    float mv = fmaxf(al0 ? o0 : NEGINF, al1 ? o1 : NEGINF);
#pragma unroll
    for (int o = 1; o < 64; o <<= 1) mv = fmaxf(mv, __shfl_xor(mv, o));
    if (l == 0) {
      selEg[h * 2048 + qr] = bE;
      selOg[h * 2048 + qr] = bO;
      mxg[h * 2048 + qr] = mv;
    }
  }
}

// ---------------- P LDS swizzled index (per-wave slice): row, tok32 ----------------
__device__ __forceinline__ int pidx2(int r, int t) {
  return r * 32 + ((((t >> 3) ^ (r & 3)) << 3) | (t & 7));
}

// ======== K3: phase B — recompute selected chunks, exp, PV. block=(qb,kvh), wave=head. ========
__global__ __launch_bounds__(256) void attnB(const unsigned short* __restrict__ Qh,
                                             const unsigned short* __restrict__ K2h,
                                             const unsigned short* __restrict__ V2,
                                             const u64* __restrict__ selEg,
                                             const u64* __restrict__ selOg,
                                             const float* __restrict__ mxg,
                                             unsigned short* __restrict__ AO) {
  __shared__ __align__(16) unsigned short Pls[4][512];
  __shared__ int clistS[4][128];

  const int qb = (int)gridDim.x - 1 - (int)blockIdx.x;   // heavy blocks first
  const int kvh = blockIdx.y;
  const int q0 = qb * 16;
  const int nct = qb + 1;
  const int tid = threadIdx.x;
  const int w = tid >> 6, l = tid & 63;
  const int lr = l & 15, lg = l >> 4;
  const int h = kvh * 4 + w;

  // Q hi fragments: row = lr, k = lg*8 + i
  bf16x8 qfh[4];
  {
    const unsigned short* qph = Qh + (long)(q0 + lr) * 4096 + h * 128 + lg * 8;
#pragma unroll
    for (int ks = 0; ks < 4; ++ks) qfh[ks] = *(const bf16x8*)(qph + ks * 32);
  }

  // per-row selection data (lane lr holds row lr)
  u64 myE = selEg[h * 2048 + q0 + lr];
  u64 myO = selOg[h * 2048 + q0 + lr];
  float mymx = mxg[h * 2048 + q0 + lr];

  u64 uE = myE, uO = myO;
#pragma unroll
  for (int o = 1; o < 16; o <<= 1) {
    uE |= __shfl_xor(uE, o);
    uO |= __shfl_xor(uO, o);
  }
  float mxj[4];
  u64 selE[4], selO[4];
#pragma unroll
  for (int j = 0; j < 4; ++j) {
    mxj[j] = __shfl(mymx, lg * 4 + j);
    selE[j] = __shfl(myE, lg * 4 + j);
    selO[j] = __shfl(myO, lg * 4 + j);
  }

  unsigned short* Pw = Pls[w];
  int* cl = clistS[w];

  // per-wave union chunk list (init/top8 from masks, plus recent window)
  const int c0 = 2 * l, c1 = 2 * l + 1;
  bool s0ok = (c0 < nct) && (((uE >> l) & 1ull) || (c0 >= qb - 7));
  bool s1ok = (c1 < nct) && (((uO >> l) & 1ull) || (c1 >= qb - 7));
  u64 bA = __ballot(s0ok);
  u64 bB = __ballot(s1ok);
  const int cntA = __popcll(bA);
  const int nsel = cntA + __popcll(bB);
  if (s0ok) cl[__popcll(bA & ((1ull << l) - 1ull))] = c0;
  if (s1ok) cl[cntA + __popcll(bB & ((1ull << l) - 1ull))] = c1;

  const unsigned short* kbh = K2h + (long)kvh * 128 * 2048;

  f32x4 pacc[8] = {};
  float psum[4] = {0.f, 0.f, 0.f, 0.f};
  const int np = (nsel + 1) >> 1;
  for (int pi = 0; pi < np; ++pi) {
    const int cA = cl[2 * pi];
    const int iB = 2 * pi + 1;
    const int cB = (iB < nsel) ? cl[iB] : cA;
#pragma unroll
    for (int half = 0; half < 2; ++half) {
      const int c = half ? cB : cA;
      const bool vslot = (2 * pi + half) < nsel;
      const unsigned short* ph = kbh + (long)c * 2048 + l * 8;
      f32x4 acc = {};
#pragma unroll
      for (int ks = 0; ks < 4; ++ks) {
        bf16x8 kf = *(const bf16x8*)(ph + ks * 512);
        acc = __builtin_amdgcn_mfma_f32_16x16x32_bf16(qfh[ks], kf, acc, 0, 0, 0);
      }
#pragma unroll
      for (int j = 0; j < 4; ++j) {
        const int r = lg * 4 + j;
        const int qrr = q0 + r;
        const int tok = c * 16 + lr;
        u64 sm = (c & 1) ? selO[j] : selE[j];
        bool sel = (sm >> (c >> 1)) & 1ull;
        bool al = vslot && (tok <= qrr) && (sel || (tok > qrr - 128));
        float p = al ? __expf(acc[j] - mxj[j]) : 0.f;
        unsigned short pb = f2bf(p);
        psum[j] += bf2f(pb);
        Pw[pidx2(r, half * 16 + lr)] = pb;
      }
    }
    bf16x8 pa = *(const bf16x8*)&Pw[pidx2(lr, lg * 8)];
    const int csel = (lg < 2) ? cA : cB;
    const unsigned short* vp = V2 + (long)(kvh * 128 + csel) * 2048 + ((lg & 1) * 16 + lr) * 8;
#pragma unroll
    for (int dblk = 0; dblk < 8; ++dblk) {
      bf16x8 vf = *(const bf16x8*)(vp + dblk * 256);
      pacc[dblk] = __builtin_amdgcn_mfma_f32_16x16x32_bf16(pa, vf, pacc[dblk], 0, 0, 0);
    }
  }

  // epilogue: per-row denom (butterfly over lr) + scaled store
#pragma unroll
  for (int j = 0; j < 4; ++j) {
    float s = psum[j];
    s += __shfl_xor(s, 1); s += __shfl_xor(s, 2);
    s += __shfl_xor(s, 4); s += __shfl_xor(s, 8);
    const float rd = 1.0f / s;
    const int r = lg * 4 + j;
#pragma unroll
    for (int dblk = 0; dblk < 8; ++dblk)
      AO[(long)(q0 + r) * 4096 + h * 128 + dblk * 16 + lr] = f2bf(pacc[dblk][j] * rd);
  }
}

// ---------------- launch ----------------
extern "C" void kernel_launch(void* const* d_in, const int* in_sizes, int n_in,
                              void* d_out, int out_size, void* d_ws, size_t ws_size,
                              hipStream_t stream) {
  const float* hidden = (const float*)d_in[0];
  const float* wq = (const float*)d_in[1];
  const float* wk = (const float*)d_in[2];
  const float* wv = (const float*)d_in[3];
  const float* wo = (const float*)d_in[4];
  float* out = (float*)d_out;

  unsigned short* hb_hi = (unsigned short*)d_ws;          // [2048][4096]
  unsigned short* hb_lo = hb_hi + (size_t)2048 * 4096;
  unsigned short* wq_hi = hb_lo + (size_t)2048 * 4096;    // [4096][4096]
  unsigned short* wq_lo = wq_hi + (size_t)4096 * 4096;
  unsigned short* wk_hi = wq_lo + (size_t)4096 * 4096;    // [1024][4096]
  unsigned short* wk_lo = wk_hi + (size_t)1024 * 4096;
  unsigned short* wv_b  = wk_lo + (size_t)1024 * 4096;    // [1024][4096]
  unsigned short* wo_b  = wv_b  + (size_t)1024 * 4096;    // [4096][4096]
  float* Qf = (float*)(wo_b + (size_t)4096 * 4096);       // [2048][4096] fp32
  float* Kf = Qf + (size_t)2048 * 4096;                   // [2048][1024] fp32
  unsigned short* V2 = (unsigned short*)(Kf + (size_t)2048 * 1024);  // frag-major
  // aliases (stream-ordered lifetimes):
  unsigned short* Qhi = wq_hi;        // wq splits dead after Q-proj GEMM
  unsigned short* Qlo = wq_lo;
  unsigned short* K2h = wk_hi;        // wk splits dead after K-proj GEMM
  unsigned short* K2l = wk_lo;
  unsigned short* AO  = hb_hi;        // hidden splits dead after V GEMM
  float* ctab = (float*)wv_b;         // wv_b dead after V GEMM
  float* stab = ctab + 2048 * 64;
  float* cmaxg = Qf;                  // Qf dead after rope_apply (33.5 MB, exact fit)
  u64* selEg = (u64*)Kf;              // Kf dead after rope_apply
  u64* selOg = selEg + 32 * 2048;
  float* mxg = (float*)(selOg + 32 * 2048);

  cvt_split<<<8192, 256, 0, stream>>>(hidden, hb_hi, hb_lo, 2097152);
  cvt_split<<<16384, 256, 0, stream>>>(wq, wq_hi, wq_lo, 4194304);
  cvt_split<<<4096, 256, 0, stream>>>(wk, wk_hi, wk_lo, 1048576);
  cvt_bf16<<<4096, 256, 0, stream>>>(wv, wv_b, 1048576);
  cvt_bf16<<<16384, 256, 0, stream>>>(wo, wo_b, 4194304);

  gemm_bt3<<<dim3(32, 16), 256, 0, stream>>>(hb_hi, hb_lo, wq_hi, wq_lo, Qf, 2048, 4096, 4096);
  gemm_bt3<<<dim3(8, 16), 256, 0, stream>>>(hb_hi, hb_lo, wk_hi, wk_lo, Kf, 2048, 1024, 4096);
  gemm_bt<4><<<dim3(8, 16), 256, 0, stream>>>(hb_hi, wv_b, V2, 2048, 1024, 4096);

  rope_table<<<512, 256, 0, stream>>>(ctab, stab);
  rope_apply<<<5120, 256, 0, stream>>>(Qf, Kf, ctab, stab, Qhi, Qlo, K2h, K2l);

  cmax_gemm<<<dim3(16, 32), 256, 0, stream>>>(Qhi, Qlo, K2h, K2l, cmaxg);
  select_kernel<<<dim3(32, 32), 256, 0, stream>>>(cmaxg, selEg, selOg, mxg);
  attnB<<<dim3(128, 8), 256, 0, stream>>>(Qhi, K2h, V2, selEg, selOg, mxg, AO);

  gemm_bt<2><<<dim3(32, 16), 256, 0, stream>>>(AO, wo_b, out, 2048, 4096, 4096);
}

// Round 6
// 897.900 us; speedup vs baseline: 1.0737x; 1.0737x over previous
//
#include <hip/hip_runtime.h>
#include <math.h>

typedef __attribute__((ext_vector_type(4))) float f32x4;
typedef __attribute__((ext_vector_type(2))) float f32x2;
typedef __attribute__((ext_vector_type(8))) __bf16 bf16x8;
typedef __attribute__((ext_vector_type(4))) unsigned short us4;
typedef unsigned long long u64;

__device__ __forceinline__ unsigned short f2bf(float f) {
  unsigned int u = __float_as_uint(f);
  u += 0x7fffu + ((u >> 16) & 1u);            // RNE
  return (unsigned short)(u >> 16);
}
__device__ __forceinline__ float bf2f(unsigned short h) {
  return __uint_as_float(((unsigned int)h) << 16);
}

__device__ __forceinline__ void gload16(const void* g, void* l) {
  __builtin_amdgcn_global_load_lds(
      (__attribute__((address_space(1))) void*)g,
      (__attribute__((address_space(3))) void*)l, 16, 0, 0);
}

// ---------------- fp32 -> bf16 convert (plain) ----------------
__global__ __launch_bounds__(256) void cvt_bf16(const float* __restrict__ in,
                                                unsigned short* __restrict__ out, int n4) {
  int i = blockIdx.x * 256 + threadIdx.x;
  if (i < n4) {
    float4 v = ((const float4*)in)[i];
    us4 o;
    o[0] = f2bf(v.x); o[1] = f2bf(v.y); o[2] = f2bf(v.z); o[3] = f2bf(v.w);
    ((us4*)out)[i] = o;
  }
}

// ---------------- fp32 -> (hi, lo) bf16 split ----------------
__global__ __launch_bounds__(256) void cvt_split(const float* __restrict__ in,
                                                 unsigned short* __restrict__ hi,
                                                 unsigned short* __restrict__ lo, int n4) {
  int i = blockIdx.x * 256 + threadIdx.x;
  if (i < n4) {
    float4 v = ((const float4*)in)[i];
    us4 h, l;
    float vv[4] = {v.x, v.y, v.z, v.w};
#pragma unroll
    for (int j = 0; j < 4; ++j) {
      unsigned short hh = f2bf(vv[j]);
      h[j] = hh;
      l[j] = f2bf(vv[j] - bf2f(hh));
    }
    ((us4*)hi)[i] = h;
    ((us4*)lo)[i] = l;
  }
}

// ---------------- GEMM: C = A * B^T (bf16 in, fp32 acc) ----------------
// SM=2: fp32 row-major store. SM=4: bf16 V2 fragment-major store (N=1024 layout).
template<int SM>
__global__ __launch_bounds__(256) void gemm_bt(const unsigned short* __restrict__ A,
                                               const unsigned short* __restrict__ B,
                                               void* __restrict__ C,
                                               int M, int N, int K) {
  __shared__ __align__(16) unsigned short As[128 * 32];
  __shared__ __align__(16) unsigned short Bs[128 * 32];
  const int tid = threadIdx.x;
  const int w = tid >> 6, l = tid & 63;
  const int wm = w >> 1, wn = w & 1;
  const int lr = l & 15, lg = l >> 4;
  const long m0 = (long)blockIdx.y * 128, n0 = (long)blockIdx.x * 128;

  f32x4 acc[4][4] = {};

  const int c0 = w * 128 + l;
  const int c1 = c0 + 64;
  const unsigned short* gA0 = A + (m0 + (c0 >> 2)) * K + (c0 & 3) * 8;
  const unsigned short* gA1 = A + (m0 + (c1 >> 2)) * K + (c1 & 3) * 8;
  const unsigned short* gB0 = B + (n0 + (c0 >> 2)) * K + (c0 & 3) * 8;
  const unsigned short* gB1 = B + (n0 + (c1 >> 2)) * K + (c1 & 3) * 8;

  for (int kt = 0; kt < K; kt += 32) {
    gload16(gA0 + kt, &As[(w * 128) * 8]);
    gload16(gA1 + kt, &As[(w * 128 + 64) * 8]);
    gload16(gB0 + kt, &Bs[(w * 128) * 8]);
    gload16(gB1 + kt, &Bs[(w * 128 + 64) * 8]);
    __syncthreads();
    bf16x8 af[4], bfr[4];
#pragma unroll
    for (int mi = 0; mi < 4; ++mi)
      af[mi] = *(const bf16x8*)&As[(wm * 64 + mi * 16 + lr) * 32 + lg * 8];
#pragma unroll
    for (int ni = 0; ni < 4; ++ni)
      bfr[ni] = *(const bf16x8*)&Bs[(wn * 64 + ni * 16 + lr) * 32 + lg * 8];
#pragma unroll
    for (int mi = 0; mi < 4; ++mi)
#pragma unroll
      for (int ni = 0; ni < 4; ++ni)
        acc[mi][ni] = __builtin_amdgcn_mfma_f32_16x16x32_bf16(af[mi], bfr[ni], acc[mi][ni], 0, 0, 0);
    __syncthreads();
  }

#pragma unroll
  for (int mi = 0; mi < 4; ++mi)
#pragma unroll
    for (int ni = 0; ni < 4; ++ni)
#pragma unroll
      for (int j = 0; j < 4; ++j) {
        long r = m0 + wm * 64 + mi * 16 + lg * 4 + j;
        long cc = n0 + wn * 64 + ni * 16 + lr;
        float v = acc[mi][ni][j];
        if (SM == 2) {
          ((float*)C)[r * N + cc] = v;
        } else {  // SM==4: V2 fragment-major
          int kvh = (int)(cc >> 7), d = (int)(cc & 127);
          int c = (int)(r >> 4), t = (int)(r & 15);
          long idx = ((long)(kvh * 128 + c) * 8 + (d >> 4)) * 256 + ((t >> 3) * 16 + (d & 15)) * 8 + (t & 7);
          ((unsigned short*)C)[idx] = f2bf(v);
        }
      }
}

// ---------------- fused split GEMM: C = Ah*Bh^T + Al*Bh^T + Ah*Bl^T (fp32 out) ----------------
__global__ __launch_bounds__(256) void gemm_bt3(const unsigned short* __restrict__ Ah,
                                                const unsigned short* __restrict__ Al,
                                                const unsigned short* __restrict__ Bh,
                                                const unsigned short* __restrict__ Bl,
                                                float* __restrict__ C,
                                                int M, int N, int K) {
  __shared__ __align__(16) unsigned short Ash[128 * 32];
  __shared__ __align__(16) unsigned short Asl[128 * 32];
  __shared__ __align__(16) unsigned short Bsh[128 * 32];
  __shared__ __align__(16) unsigned short Bsl[128 * 32];
  const int tid = threadIdx.x;
  const int w = tid >> 6, l = tid & 63;
  const int wm = w >> 1, wn = w & 1;
  const int lr = l & 15, lg = l >> 4;
  const long m0 = (long)blockIdx.y * 128, n0 = (long)blockIdx.x * 128;

  f32x4 acc[4][4] = {};

  const int c0 = w * 128 + l;
  const int c1 = c0 + 64;
  const long oA0 = (m0 + (c0 >> 2)) * K + (c0 & 3) * 8;
  const long oA1 = (m0 + (c1 >> 2)) * K + (c1 & 3) * 8;
  const long oB0 = (n0 + (c0 >> 2)) * K + (c0 & 3) * 8;
  const long oB1 = (n0 + (c1 >> 2)) * K + (c1 & 3) * 8;

  for (int kt = 0; kt < K; kt += 32) {
    gload16(Ah + oA0 + kt, &Ash[(w * 128) * 8]);
    gload16(Ah + oA1 + kt, &Ash[(w * 128 + 64) * 8]);
    gload16(Al + oA0 + kt, &Asl[(w * 128) * 8]);
    gload16(Al + oA1 + kt, &Asl[(w * 128 + 64) * 8]);
    gload16(Bh + oB0 + kt, &Bsh[(w * 128) * 8]);
    gload16(Bh + oB1 + kt, &Bsh[(w * 128 + 64) * 8]);
    gload16(Bl + oB0 + kt, &Bsl[(w * 128) * 8]);
    gload16(Bl + oB1 + kt, &Bsl[(w * 128 + 64) * 8]);
    __syncthreads();
    bf16x8 afh[4], afl[4], bfh[4], bfl[4];
#pragma unroll
    for (int mi = 0; mi < 4; ++mi) {
      afh[mi] = *(const bf16x8*)&Ash[(wm * 64 + mi * 16 + lr) * 32 + lg * 8];
      afl[mi] = *(const bf16x8*)&Asl[(wm * 64 + mi * 16 + lr) * 32 + lg * 8];
    }
#pragma unroll
    for (int ni = 0; ni < 4; ++ni) {
      bfh[ni] = *(const bf16x8*)&Bsh[(wn * 64 + ni * 16 + lr) * 32 + lg * 8];
      bfl[ni] = *(const bf16x8*)&Bsl[(wn * 64 + ni * 16 + lr) * 32 + lg * 8];
    }
#pragma unroll
    for (int mi = 0; mi < 4; ++mi)
#pragma unroll
      for (int ni = 0; ni < 4; ++ni) {
        acc[mi][ni] = __builtin_amdgcn_mfma_f32_16x16x32_bf16(afh[mi], bfh[ni], acc[mi][ni], 0, 0, 0);
        acc[mi][ni] = __builtin_amdgcn_mfma_f32_16x16x32_bf16(afl[mi], bfh[ni], acc[mi][ni], 0, 0, 0);
        acc[mi][ni] = __builtin_amdgcn_mfma_f32_16x16x32_bf16(afh[mi], bfl[ni], acc[mi][ni], 0, 0, 0);
      }
    __syncthreads();
  }

#pragma unroll
  for (int mi = 0; mi < 4; ++mi)
#pragma unroll
    for (int ni = 0; ni < 4; ++ni)
#pragma unroll
      for (int j = 0; j < 4; ++j) {
        long r = m0 + wm * 64 + mi * 16 + lg * 4 + j;
        long cc = n0 + wn * 64 + ni * 16 + lr;
        C[r * N + cc] = acc[mi][ni][j];
      }
}

// ---------------- K2 fragment-major index: K element (s, kvh, d) ----------------
__device__ __forceinline__ long k2idx(int kvh, int s, int d) {
  int ct = s >> 4;
  int lane = (((d & 31) >> 3) << 4) | (s & 15);
  return ((long)(kvh * 128 + ct) * 4 + (d >> 5)) * 512 + lane * 8 + (d & 7);
}

// ---------------- RoPE angle table ----------------
__global__ __launch_bounds__(256) void rope_table(float* __restrict__ ctab,
                                                  float* __restrict__ stab) {
  int idx = blockIdx.x * 256 + threadIdx.x;   // 2048*64
  if (idx >= 2048 * 64) return;
  int s = idx >> 6, d = idx & 63;
  float inv = powf(10000.0f, -(float)d * (1.0f / 64.0f));
  float ang = (float)s * inv;
  ctab[idx] = cosf(ang);
  stab[idx] = sinf(ang);
}

// ---------------- RoPE apply: fp32 -> Q (row-major hi/lo, pre-scaled), K (frag-major hi/lo) ----------------
__global__ __launch_bounds__(256) void rope_apply(const float* __restrict__ Qf,
                                                  const float* __restrict__ Kf,
                                                  const float* __restrict__ ctab,
                                                  const float* __restrict__ stab,
                                                  unsigned short* __restrict__ Qh,
                                                  unsigned short* __restrict__ Ql,
                                                  unsigned short* __restrict__ K2h,
                                                  unsigned short* __restrict__ K2l) {
  int t = blockIdx.x * 256 + threadIdx.x;     // 2048*40*16
  if (t >= 2048 * 40 * 16) return;
  int s = t / 640;
  int rem = t - s * 640;
  int hd = rem >> 4;
  int d4 = (rem & 15) * 4;
  float4 cv = *(const float4*)&ctab[s * 64 + d4];
  float4 sv = *(const float4*)&stab[s * 64 + d4];
  float cc[4] = {cv.x, cv.y, cv.z, cv.w};
  float ss[4] = {sv.x, sv.y, sv.z, sv.w};
  us4 h1, l1, h2, l2;
  if (hd < 32) {
    long row = (long)s * 4096 + hd * 128;
    float4 u1 = *(const float4*)&Qf[row + d4];
    float4 u2 = *(const float4*)&Qf[row + 64 + d4];
    float a1[4] = {u1.x, u1.y, u1.z, u1.w};
    float a2[4] = {u2.x, u2.y, u2.z, u2.w};
    const float scale = 0.08838834764831845f;  // 1/sqrt(128)
#pragma unroll
    for (int j = 0; j < 4; ++j) {
      float y1 = (a1[j] * cc[j] - a2[j] * ss[j]) * scale;
      float y2 = (a2[j] * cc[j] + a1[j] * ss[j]) * scale;
      h1[j] = f2bf(y1); l1[j] = f2bf(y1 - bf2f(h1[j]));
      h2[j] = f2bf(y2); l2[j] = f2bf(y2 - bf2f(h2[j]));
    }
    *(us4*)&Qh[row + d4] = h1;      *(us4*)&Ql[row + d4] = l1;
    *(us4*)&Qh[row + 64 + d4] = h2; *(us4*)&Ql[row + 64 + d4] = l2;
  } else {
    int kvh = hd - 32;
    long row = (long)s * 1024 + kvh * 128;
    float4 u1 = *(const float4*)&Kf[row + d4];
    float4 u2 = *(const float4*)&Kf[row + 64 + d4];
    float a1[4] = {u1.x, u1.y, u1.z, u1.w};
    float a2[4] = {u2.x, u2.y, u2.z, u2.w};
#pragma unroll
    for (int j = 0; j < 4; ++j) {
      float y1 = a1[j] * cc[j] - a2[j] * ss[j];
      float y2 = a2[j] * cc[j] + a1[j] * ss[j];
      h1[j] = f2bf(y1); l1[j] = f2bf(y1 - bf2f(h1[j]));
      h2[j] = f2bf(y2); l2[j] = f2bf(y2 - bf2f(h2[j]));
    }
    long i1 = k2idx(kvh, s, d4);
    long i2 = k2idx(kvh, s, d4 + 64);
    *(us4*)&K2h[i1] = h1; *(us4*)&K2l[i1] = l1;
    *(us4*)&K2h[i2] = h2; *(us4*)&K2l[i2] = l2;
  }
}

// ======== K1: cmax GEMM, 4-deep counted-vmcnt pipeline (T3+T4 minimal form). ========
// block = (q-panel of 128 rows, head); 4 waves x 32 rows; 32-token K panels.
// Per-wave vmem sequence is deterministic: 4 stage-loads + 4 cmax-stores per iteration.
// vmcnt target = 4*(panels issued beyond kp) + 4*(stores issued after L(kp)).
__global__ __launch_bounds__(256, 2) void cmax_gemm(const unsigned short* __restrict__ Qh,
                                                    const unsigned short* __restrict__ Ql,
                                                    const unsigned short* __restrict__ K2h,
                                                    const unsigned short* __restrict__ K2l,
                                                    float* __restrict__ cmaxg) {
  __shared__ __align__(16) unsigned short Ksh[4][4096];  // 4 x 8KB hi (32-tok panel)
  __shared__ __align__(16) unsigned short Ksl[4][4096];  // 4 x 8KB lo
  const int qp = 15 - (int)blockIdx.x;                   // heavy panels first
  const int h = blockIdx.y;
  const int kvh = h >> 2;
  const int q0 = qp * 128;
  const int tid = threadIdx.x;
  const int w = tid >> 6, l = tid & 63;
  const int lr = l & 15, lg = l >> 4;
  const int npan = 4 * (qp + 1);
  const float NEGINF = -__builtin_inff();

  // Q B-frags in registers: wave w rows q0 + w*32 + rg*16 + lr
  bf16x8 qfh[2][4], qfl[2][4];
#pragma unroll
  for (int rg = 0; rg < 2; ++rg) {
    const unsigned short* qph = Qh + (long)(q0 + w * 32 + rg * 16 + lr) * 4096 + h * 128 + lg * 8;
    const unsigned short* qpl = Ql + (long)(q0 + w * 32 + rg * 16 + lr) * 4096 + h * 128 + lg * 8;
#pragma unroll
    for (int ks = 0; ks < 4; ++ks) {
      qfh[rg][ks] = *(const bf16x8*)(qph + ks * 32);
      qfl[rg][ks] = *(const bf16x8*)(qpl + ks * 32);
    }
  }

  const unsigned short* kbh = K2h + (long)kvh * 128 * 2048;
  const unsigned short* kbl = K2l + (long)kvh * 128 * 2048;

  // stage one 32-token panel (8KB hi + 8KB lo, contiguous); 4 gload16 per wave
#define STAGE(kp, b)                                                       \
  {                                                                        \
    long off = (long)(kp) * 4096;                                          \
    _Pragma("unroll")                                                      \
    for (int i = 0; i < 2; ++i) {                                          \
      int cu = w * 128 + i * 64;                                           \
      gload16(kbh + off + (cu + l) * 8, &Ksh[b][cu * 8]);                  \
      gload16(kbl + off + (cu + l) * 8, &Ksl[b][cu * 8]);                  \
    }                                                                      \
  }

  STAGE(0, 0);
  if (1 < npan) STAGE(1, 1);
  if (2 < npan) STAGE(2, 2);

  for (int kp = 0; kp < npan; ++kp) {
    // exact counted wait: ensure panel kp's loads retired, keep newer panels in flight
    {
      int ahead = npan - 1 - kp; if (ahead > 2) ahead = 2;
      int st = kp; if (st > 3) st = 3;
      int tgt = 4 * ahead + 4 * st;
      if (tgt >= 20)      asm volatile("s_waitcnt vmcnt(20)" ::: "memory");
      else if (tgt >= 16) asm volatile("s_waitcnt vmcnt(16)" ::: "memory");
      else if (tgt >= 12) asm volatile("s_waitcnt vmcnt(12)" ::: "memory");
      else if (tgt >= 8)  asm volatile("s_waitcnt vmcnt(8)" ::: "memory");
      else                asm volatile("s_waitcnt vmcnt(0)" ::: "memory");
    }
    __builtin_amdgcn_s_barrier();
    __builtin_amdgcn_sched_barrier(0);
    if (kp + 3 < npan) STAGE(kp + 3, (kp + 3) & 3);
    const int b = kp & 3;
#pragma unroll
    for (int c2 = 0; c2 < 2; ++c2) {
      const int ct = kp * 2 + c2;
      bf16x8 kh[4], kl2[4];
#pragma unroll
      for (int ks = 0; ks < 4; ++ks) {
        kh[ks]  = *(const bf16x8*)&Ksh[b][(c2 * 4 + ks) * 512 + l * 8];
        kl2[ks] = *(const bf16x8*)&Ksl[b][(c2 * 4 + ks) * 512 + l * 8];
      }
#pragma unroll
      for (int rg = 0; rg < 2; ++rg) {
        f32x4 acc = {};
#pragma unroll
        for (int ks = 0; ks < 4; ++ks) {
          acc = __builtin_amdgcn_mfma_f32_16x16x32_bf16(kh[ks], qfh[rg][ks], acc, 0, 0, 0);
          acc = __builtin_amdgcn_mfma_f32_16x16x32_bf16(kh[ks], qfl[rg][ks], acc, 0, 0, 0);
          acc = __builtin_amdgcn_mfma_f32_16x16x32_bf16(kl2[ks], qfh[rg][ks], acc, 0, 0, 0);
        }
        const int rbase = q0 + w * 32 + rg * 16;
        float m;
        if (ct * 16 + 15 <= rbase) {             // fully causal for this row group
          m = fmaxf(fmaxf(acc[0], acc[1]), fmaxf(acc[2], acc[3]));
        } else {                                 // diagonal region
          m = NEGINF;
#pragma unroll
          for (int j = 0; j < 4; ++j) {
            int tok = ct * 16 + lg * 4 + j;
            if (tok <= rbase + lr) m = fmaxf(m, acc[j]);
          }
        }
        m = fmaxf(m, __shfl_xor(m, 16));
        m = fmaxf(m, __shfl_xor(m, 32));
        if (l < 16) cmaxg[(long)(h * 128 + ct) * 2048 + rbase + l] = m;
      }
    }
  }
#undef STAGE
}

// ======== K2: per-row top-8 selection. block = (64-row group, head). ========
__global__ __launch_bounds__(256) void select_kernel(const float* __restrict__ cmaxg,
                                                     u64* __restrict__ selEg,
                                                     u64* __restrict__ selOg,
                                                     float* __restrict__ mxg) {
  __shared__ float Lc[128 * 65];                  // [ct][row], padded
  const int r0 = (int)blockIdx.x * 64;
  const int h = blockIdx.y;
  const int tid = threadIdx.x;
  const int w = tid >> 6, l = tid & 63;
  const float NEGINF = -__builtin_inff();

  for (int i = tid; i < 128 * 16; i += 256) {
    int ct = i >> 4, rq = (i & 15) * 4;
    float4 v = *(const float4*)&cmaxg[(long)(h * 128 + ct) * 2048 + r0 + rq];
    Lc[ct * 65 + rq]     = v.x;
    Lc[ct * 65 + rq + 1] = v.y;
    Lc[ct * 65 + rq + 2] = v.z;
    Lc[ct * 65 + rq + 3] = v.w;
  }
  __syncthreads();

  const int c0 = 2 * l, c1 = 2 * l + 1;
#pragma unroll 1
  for (int rs = 0; rs < 16; ++rs) {
    const int rloc = w * 16 + rs;
    const int qr = r0 + rloc;
    const int nctr = (qr >> 4) + 1;
    float v0 = (c0 < nctr) ? Lc[c0 * 65 + rloc] : NEGINF;
    float v1 = (c1 < nctr) ? Lc[c1 * 65 + rloc] : NEGINF;
    const float o0 = v0, o1 = v1;
    float T = NEGINF;
    for (int it = 0; it < 8; ++it) {
      float m = fmaxf(v0, v1);
#pragma unroll
      for (int o = 1; o < 64; o <<= 1) m = fmaxf(m, __shfl_xor(m, o));
      u64 bal = __ballot((v0 == m) || (v1 == m));
      int first = __ffsll(bal) - 1;
      if (l == first) { if (v0 == m) v0 = NEGINF; else v1 = NEGINF; }
      T = m;
    }
    bool okc0 = (c0 < nctr) && ((c0 < 8) || (o0 >= T));
    bool okc1 = (c1 < nctr) && ((c1 < 8) || (o1 >= T));
    u64 bE = __ballot(okc0);
    u64 bO = __ballot(okc1);
    bool al0 = (c0 < nctr) && (okc0 || (c0 * 16 + 15 > qr - 128));
    bool al1 = (c1 < nctr) && (okc1 || (c1 * 16 + 15 > qr - 128));
    float mv = fmaxf(al0 ? o0 : NEGINF, al1 ? o1 : NEGINF);
#pragma unroll
    for (int o = 1; o < 64; o <<= 1) mv = fmaxf(mv, __shfl_xor(mv, o));
    if (l == 0) {
      selEg[h * 2048 + qr] = bE;
      selOg[h * 2048 + qr] = bO;
      mxg[h * 2048 + qr] = mv;
    }
  }
}

// ---------------- P LDS swizzled index (per-wave slice): row, tok32 ----------------
__device__ __forceinline__ int pidx2(int r, int t) {
  return r * 32 + ((((t >> 3) ^ (r & 3)) << 3) | (t & 7));
}

// ======== K3: phase B — recompute selected chunks, exp, PV. block=(qb,kvh), wave=head. ========
__global__ __launch_bounds__(256) void attnB(const unsigned short* __restrict__ Qh,
                                             const unsigned short* __restrict__ K2h,
                                             const unsigned short* __restrict__ V2,
                                             const u64* __restrict__ selEg,
                                             const u64* __restrict__ selOg,
                                             const float* __restrict__ mxg,
                                             unsigned short* __restrict__ AO) {
  __shared__ __align__(16) unsigned short Pls[4][512];
  __shared__ int clistS[4][128];

  const int qb = (int)gridDim.x - 1 - (int)blockIdx.x;   // heavy blocks first
  const int kvh = blockIdx.y;
  const int q0 = qb * 16;
  const int nct = qb + 1;
  const int tid = threadIdx.x;
  const int w = tid >> 6, l = tid & 63;
  const int lr = l & 15, lg = l >> 4;
  const int h = kvh * 4 + w;

  // Q hi fragments: row = lr, k = lg*8 + i
  bf16x8 qfh[4];
  {
    const unsigned short* qph = Qh + (long)(q0 + lr) * 4096 + h * 128 + lg * 8;
#pragma unroll
    for (int ks = 0; ks < 4; ++ks) qfh[ks] = *(const bf16x8*)(qph + ks * 32);
  }

  // per-row selection data (lane lr holds row lr)
  u64 myE = selEg[h * 2048 + q0 + lr];
  u64 myO = selOg[h * 2048 + q0 + lr];
  float mymx = mxg[h * 2048 + q0 + lr];

  u64 uE = myE, uO = myO;
#pragma unroll
  for (int o = 1; o < 16; o <<= 1) {
    uE |= __shfl_xor(uE, o);
    uO |= __shfl_xor(uO, o);
  }
  float mxj[4];
  u64 selE[4], selO[4];
#pragma unroll
  for (int j = 0; j < 4; ++j) {
    mxj[j] = __shfl(mymx, lg * 4 + j);
    selE[j] = __shfl(myE, lg * 4 + j);
    selO[j] = __shfl(myO, lg * 4 + j);
  }

  unsigned short* Pw = Pls[w];
  int* cl = clistS[w];

  // per-wave union chunk list (init/top8 from masks, plus recent window)
  const int c0 = 2 * l, c1 = 2 * l + 1;
  bool s0ok = (c0 < nct) && (((uE >> l) & 1ull) || (c0 >= qb - 7));
  bool s1ok = (c1 < nct) && (((uO >> l) & 1ull) || (c1 >= qb - 7));
  u64 bA = __ballot(s0ok);
  u64 bB = __ballot(s1ok);
  const int cntA = __popcll(bA);
  const int nsel = cntA + __popcll(bB);
  if (s0ok) cl[__popcll(bA & ((1ull << l) - 1ull))] = c0;
  if (s1ok) cl[cntA + __popcll(bB & ((1ull << l) - 1ull))] = c1;

  const unsigned short* kbh = K2h + (long)kvh * 128 * 2048;

  f32x4 pacc[8] = {};
  float psum[4] = {0.f, 0.f, 0.f, 0.f};
  const int np = (nsel + 1) >> 1;
  for (int pi = 0; pi < np; ++pi) {
    const int cA = cl[2 * pi];
    const int iB = 2 * pi + 1;
    const int cB = (iB < nsel) ? cl[iB] : cA;

    // issue V loads for this iteration early (independent of P) so their L2
    // latency hides under the QK/exp/P phase
    const int csel = (lg < 2) ? cA : cB;
    const unsigned short* vp = V2 + (long)(kvh * 128 + csel) * 2048 + ((lg & 1) * 16 + lr) * 8;
    bf16x8 vf[8];
#pragma unroll
    for (int dblk = 0; dblk < 8; ++dblk) vf[dblk] = *(const bf16x8*)(vp + dblk * 256);

#pragma unroll
    for (int half = 0; half < 2; ++half) {
      const int c = half ? cB : cA;
      const bool vslot = (2 * pi + half) < nsel;
      const unsigned short* ph = kbh + (long)c * 2048 + l * 8;
      f32x4 acc = {};
#pragma unroll
      for (int ks = 0; ks < 4; ++ks) {
        bf16x8 kf = *(const bf16x8*)(ph + ks * 512);
        acc = __builtin_amdgcn_mfma_f32_16x16x32_bf16(qfh[ks], kf, acc, 0, 0, 0);
      }
#pragma unroll
      for (int j = 0; j < 4; ++j) {
        const int r = lg * 4 + j;
        const int qrr = q0 + r;
        const int tok = c * 16 + lr;
        u64 sm = (c & 1) ? selO[j] : selE[j];
        bool sel = (sm >> (c >> 1)) & 1ull;
        bool al = vslot && (tok <= qrr) && (sel || (tok > qrr - 128));
        float p = al ? __expf(acc[j] - mxj[j]) : 0.f;
        unsigned short pb = f2bf(p);
        psum[j] += bf2f(pb);
        Pw[pidx2(r, half * 16 + lr)] = pb;
      }
    }
    bf16x8 pa = *(const bf16x8*)&Pw[pidx2(lr, lg * 8)];
#pragma unroll
    for (int dblk = 0; dblk < 8; ++dblk)
      pacc[dblk] = __builtin_amdgcn_mfma_f32_16x16x32_bf16(pa, vf[dblk], pacc[dblk], 0, 0, 0);
  }

  // epilogue: per-row denom (butterfly over lr) + scaled store
#pragma unroll
  for (int j = 0; j < 4; ++j) {
    float s = psum[j];
    s += __shfl_xor(s, 1); s += __shfl_xor(s, 2);
    s += __shfl_xor(s, 4); s += __shfl_xor(s, 8);
    const float rd = 1.0f / s;
    const int r = lg * 4 + j;
#pragma unroll
    for (int dblk = 0; dblk < 8; ++dblk)
      AO[(long)(q0 + r) * 4096 + h * 128 + dblk * 16 + lr] = f2bf(pacc[dblk][j] * rd);
  }
}

// ---------------- launch ----------------
extern "C" void kernel_launch(void* const* d_in, const int* in_sizes, int n_in,
                              void* d_out, int out_size, void* d_ws, size_t ws_size,
                              hipStream_t stream) {
  const float* hidden = (const float*)d_in[0];
  const float* wq = (const float*)d_in[1];
  const float* wk = (const float*)d_in[2];
  const float* wv = (const float*)d_in[3];
  const float* wo = (const float*)d_in[4];
  float* out = (float*)d_out;

  unsigned short* hb_hi = (unsigned short*)d_ws;          // [2048][4096]
  unsigned short* hb_lo = hb_hi + (size_t)2048 * 4096;
  unsigned short* wq_hi = hb_lo + (size_t)2048 * 4096;    // [4096][4096]
  unsigned short* wq_lo = wq_hi + (size_t)4096 * 4096;
  unsigned short* wk_hi = wq_lo + (size_t)4096 * 4096;    // [1024][4096]
  unsigned short* wk_lo = wk_hi + (size_t)1024 * 4096;
  unsigned short* wv_b  = wk_lo + (size_t)1024 * 4096;    // [1024][4096]
  unsigned short* wo_b  = wv_b  + (size_t)1024 * 4096;    // [4096][4096]
  float* Qf = (float*)(wo_b + (size_t)4096 * 4096);       // [2048][4096] fp32
  float* Kf = Qf + (size_t)2048 * 4096;                   // [2048][1024] fp32
  unsigned short* V2 = (unsigned short*)(Kf + (size_t)2048 * 1024);  // frag-major
  // aliases (stream-ordered lifetimes):
  unsigned short* Qhi = wq_hi;        // wq splits dead after Q-proj GEMM
  unsigned short* Qlo = wq_lo;
  unsigned short* K2h = wk_hi;        // wk splits dead after K-proj GEMM
  unsigned short* K2l = wk_lo;
  unsigned short* AO  = hb_hi;        // hidden splits dead after V GEMM
  float* ctab = (float*)wv_b;         // wv_b dead after V GEMM
  float* stab = ctab + 2048 * 64;
  float* cmaxg = Qf;                  // Qf dead after rope_apply (33.5 MB, exact fit)
  u64* selEg = (u64*)Kf;              // Kf dead after rope_apply
  u64* selOg = selEg + 32 * 2048;
  float* mxg = (float*)(selOg + 32 * 2048);

  cvt_split<<<8192, 256, 0, stream>>>(hidden, hb_hi, hb_lo, 2097152);
  cvt_split<<<16384, 256, 0, stream>>>(wq, wq_hi, wq_lo, 4194304);
  cvt_split<<<4096, 256, 0, stream>>>(wk, wk_hi, wk_lo, 1048576);
  cvt_bf16<<<4096, 256, 0, stream>>>(wv, wv_b, 1048576);
  cvt_bf16<<<16384, 256, 0, stream>>>(wo, wo_b, 4194304);

  gemm_bt3<<<dim3(32, 16), 256, 0, stream>>>(hb_hi, hb_lo, wq_hi, wq_lo, Qf, 2048, 4096, 4096);
  gemm_bt3<<<dim3(8, 16), 256, 0, stream>>>(hb_hi, hb_lo, wk_hi, wk_lo, Kf, 2048, 1024, 4096);
  gemm_bt<4><<<dim3(8, 16), 256, 0, stream>>>(hb_hi, wv_b, V2, 2048, 1024, 4096);

  rope_table<<<512, 256, 0, stream>>>(ctab, stab);
  rope_apply<<<5120, 256, 0, stream>>>(Qf, Kf, ctab, stab, Qhi, Qlo, K2h, K2l);

  cmax_gemm<<<dim3(16, 32), 256, 0, stream>>>(Qhi, Qlo, K2h, K2l, cmaxg);
  select_kernel<<<dim3(32, 32), 256, 0, stream>>>(cmaxg, selEg, selOg, mxg);
  attnB<<<dim3(128, 8), 256, 0, stream>>>(Qhi, K2h, V2, selEg, selOg, mxg, AO);

  gemm_bt<2><<<dim3(32, 16), 256, 0, stream>>>(AO, wo_b, out, 2048, 4096, 4096);
}

// Round 7
// 808.155 us; speedup vs baseline: 1.1930x; 1.1110x over previous
//
#include <hip/hip_runtime.h>
#include <math.h>

typedef __attribute__((ext_vector_type(4))) float f32x4;
typedef __attribute__((ext_vector_type(2))) float f32x2;
typedef __attribute__((ext_vector_type(8))) __bf16 bf16x8;
typedef __attribute__((ext_vector_type(4))) unsigned short us4;
typedef unsigned long long u64;

__device__ __forceinline__ unsigned short f2bf(float f) {
  unsigned int u = __float_as_uint(f);
  u += 0x7fffu + ((u >> 16) & 1u);            // RNE
  return (unsigned short)(u >> 16);
}
__device__ __forceinline__ float bf2f(unsigned short h) {
  return __uint_as_float(((unsigned int)h) << 16);
}

__device__ __forceinline__ void gload16(const void* g, void* l) {
  __builtin_amdgcn_global_load_lds(
      (__attribute__((address_space(1))) void*)g,
      (__attribute__((address_space(3))) void*)l, 16, 0, 0);
}

// ---------------- fused fp32 -> bf16 conversions (all 5 inputs, one kernel) ----------------
__device__ __forceinline__ void split1(const float* __restrict__ in,
                                       unsigned short* __restrict__ hi,
                                       unsigned short* __restrict__ lo, int i) {
  float4 v = ((const float4*)in)[i];
  us4 h, l;
  float vv[4] = {v.x, v.y, v.z, v.w};
#pragma unroll
  for (int j = 0; j < 4; ++j) {
    unsigned short hh = f2bf(vv[j]);
    h[j] = hh;
    l[j] = f2bf(vv[j] - bf2f(hh));
  }
  ((us4*)hi)[i] = h;
  ((us4*)lo)[i] = l;
}
__device__ __forceinline__ void plain1(const float* __restrict__ in,
                                       unsigned short* __restrict__ out, int i) {
  float4 v = ((const float4*)in)[i];
  us4 o;
  o[0] = f2bf(v.x); o[1] = f2bf(v.y); o[2] = f2bf(v.z); o[3] = f2bf(v.w);
  ((us4*)out)[i] = o;
}

__global__ __launch_bounds__(256) void cvt_all(const float* __restrict__ hidden,
                                               const float* __restrict__ wq,
                                               const float* __restrict__ wk,
                                               const float* __restrict__ wv,
                                               const float* __restrict__ wo,
                                               unsigned short* __restrict__ hb_hi,
                                               unsigned short* __restrict__ hb_lo,
                                               unsigned short* __restrict__ wq_hi,
                                               unsigned short* __restrict__ wq_lo,
                                               unsigned short* __restrict__ wk_hi,
                                               unsigned short* __restrict__ wk_lo,
                                               unsigned short* __restrict__ wv_b,
                                               unsigned short* __restrict__ wo_b) {
  int i = blockIdx.x * 256 + threadIdx.x;
  if (i < 2097152)       split1(hidden, hb_hi, hb_lo, i);
  else if (i < 6291456)  split1(wq, wq_hi, wq_lo, i - 2097152);
  else if (i < 7340032)  split1(wk, wk_hi, wk_lo, i - 6291456);
  else if (i < 8388608)  plain1(wv, wv_b, i - 7340032);
  else if (i < 12582912) plain1(wo, wo_b, i - 8388608);
}

// ---------------- GEMM: C = A * B^T, counted-vmcnt double-buffered pipeline ----------------
// SM=2: fp32 row-major store. SM=4: bf16 V2 fragment-major store (N=1024 layout).
template<int SM>
__global__ __launch_bounds__(256) void gemm_bt(const unsigned short* __restrict__ A,
                                               const unsigned short* __restrict__ B,
                                               void* __restrict__ C,
                                               int M, int N, int K) {
  __shared__ __align__(16) unsigned short As[2][4096];
  __shared__ __align__(16) unsigned short Bs[2][4096];
  const int tid = threadIdx.x;
  const int w = tid >> 6, l = tid & 63;
  const int wm = w >> 1, wn = w & 1;
  const int lr = l & 15, lg = l >> 4;
  const long m0 = (long)blockIdx.y * 128, n0 = (long)blockIdx.x * 128;

  f32x4 acc[4][4] = {};

  const int c0 = w * 128 + l;
  const int c1 = c0 + 64;
  const unsigned short* gA0 = A + (m0 + (c0 >> 2)) * K + (c0 & 3) * 8;
  const unsigned short* gA1 = A + (m0 + (c1 >> 2)) * K + (c1 & 3) * 8;
  const unsigned short* gB0 = B + (n0 + (c0 >> 2)) * K + (c0 & 3) * 8;
  const unsigned short* gB1 = B + (n0 + (c1 >> 2)) * K + (c1 & 3) * 8;

#define STAGE1(t, b)                                   \
  {                                                    \
    long kt = (long)(t) * 32;                          \
    gload16(gA0 + kt, &As[b][w * 1024]);               \
    gload16(gA1 + kt, &As[b][w * 1024 + 512]);         \
    gload16(gB0 + kt, &Bs[b][w * 1024]);               \
    gload16(gB1 + kt, &Bs[b][w * 1024 + 512]);         \
  }

  const int nt = K >> 5;
  STAGE1(0, 0);
  if (nt > 1) STAGE1(1, 1);

  for (int t = 0; t < nt; ++t) {
    if (t + 1 < nt) asm volatile("s_waitcnt vmcnt(4)" ::: "memory");
    else            asm volatile("s_waitcnt vmcnt(0)" ::: "memory");
    __builtin_amdgcn_s_barrier();
    __builtin_amdgcn_sched_barrier(0);
    const int b = t & 1;
    bf16x8 af[4], bfr[4];
#pragma unroll
    for (int mi = 0; mi < 4; ++mi)
      af[mi] = *(const bf16x8*)&As[b][(wm * 64 + mi * 16 + lr) * 32 + lg * 8];
#pragma unroll
    for (int ni = 0; ni < 4; ++ni)
      bfr[ni] = *(const bf16x8*)&Bs[b][(wn * 64 + ni * 16 + lr) * 32 + lg * 8];
#pragma unroll
    for (int mi = 0; mi < 4; ++mi)
#pragma unroll
      for (int ni = 0; ni < 4; ++ni)
        acc[mi][ni] = __builtin_amdgcn_mfma_f32_16x16x32_bf16(af[mi], bfr[ni], acc[mi][ni], 0, 0, 0);
    __builtin_amdgcn_sched_barrier(0);
    __builtin_amdgcn_s_barrier();
    __builtin_amdgcn_sched_barrier(0);
    if (t + 2 < nt) STAGE1(t + 2, b);
  }
#undef STAGE1

#pragma unroll
  for (int mi = 0; mi < 4; ++mi)
#pragma unroll
    for (int ni = 0; ni < 4; ++ni)
#pragma unroll
      for (int j = 0; j < 4; ++j) {
        long r = m0 + wm * 64 + mi * 16 + lg * 4 + j;
        long cc = n0 + wn * 64 + ni * 16 + lr;
        float v = acc[mi][ni][j];
        if (SM == 2) {
          ((float*)C)[r * N + cc] = v;
        } else {  // SM==4: V2 fragment-major
          int kvh = (int)(cc >> 7), d = (int)(cc & 127);
          int c = (int)(r >> 4), t2 = (int)(r & 15);
          long idx = ((long)(kvh * 128 + c) * 8 + (d >> 4)) * 256 + ((t2 >> 3) * 16 + (d & 15)) * 8 + (t2 & 7);
          ((unsigned short*)C)[idx] = f2bf(v);
        }
      }
}

// ---------------- fused split GEMM: C = Ah*Bh^T + Al*Bh^T + Ah*Bl^T (fp32 out) ----------------
// counted-vmcnt double-buffered pipeline (64 KB LDS, vmcnt(8) steady state)
__global__ __launch_bounds__(256) void gemm_bt3(const unsigned short* __restrict__ Ah,
                                                const unsigned short* __restrict__ Al,
                                                const unsigned short* __restrict__ Bh,
                                                const unsigned short* __restrict__ Bl,
                                                float* __restrict__ C,
                                                int M, int N, int K) {
  __shared__ __align__(16) unsigned short Ash[2][4096];
  __shared__ __align__(16) unsigned short Asl[2][4096];
  __shared__ __align__(16) unsigned short Bsh[2][4096];
  __shared__ __align__(16) unsigned short Bsl[2][4096];
  const int tid = threadIdx.x;
  const int w = tid >> 6, l = tid & 63;
  const int wm = w >> 1, wn = w & 1;
  const int lr = l & 15, lg = l >> 4;
  const long m0 = (long)blockIdx.y * 128, n0 = (long)blockIdx.x * 128;

  f32x4 acc[4][4] = {};

  const int c0 = w * 128 + l;
  const int c1 = c0 + 64;
  const long oA0 = (m0 + (c0 >> 2)) * K + (c0 & 3) * 8;
  const long oA1 = (m0 + (c1 >> 2)) * K + (c1 & 3) * 8;
  const long oB0 = (n0 + (c0 >> 2)) * K + (c0 & 3) * 8;
  const long oB1 = (n0 + (c1 >> 2)) * K + (c1 & 3) * 8;

#define STAGE3(t, b)                                        \
  {                                                         \
    long kt = (long)(t) * 32;                               \
    gload16(Ah + oA0 + kt, &Ash[b][w * 1024]);              \
    gload16(Ah + oA1 + kt, &Ash[b][w * 1024 + 512]);        \
    gload16(Al + oA0 + kt, &Asl[b][w * 1024]);              \
    gload16(Al + oA1 + kt, &Asl[b][w * 1024 + 512]);        \
    gload16(Bh + oB0 + kt, &Bsh[b][w * 1024]);              \
    gload16(Bh + oB1 + kt, &Bsh[b][w * 1024 + 512]);        \
    gload16(Bl + oB0 + kt, &Bsl[b][w * 1024]);              \
    gload16(Bl + oB1 + kt, &Bsl[b][w * 1024 + 512]);        \
  }

  const int nt = K >> 5;
  STAGE3(0, 0);
  if (nt > 1) STAGE3(1, 1);

  for (int t = 0; t < nt; ++t) {
    if (t + 1 < nt) asm volatile("s_waitcnt vmcnt(8)" ::: "memory");
    else            asm volatile("s_waitcnt vmcnt(0)" ::: "memory");
    __builtin_amdgcn_s_barrier();
    __builtin_amdgcn_sched_barrier(0);
    const int b = t & 1;
    bf16x8 afh[4], afl[4], bfh[4], bfl[4];
#pragma unroll
    for (int mi = 0; mi < 4; ++mi) {
      afh[mi] = *(const bf16x8*)&Ash[b][(wm * 64 + mi * 16 + lr) * 32 + lg * 8];
      afl[mi] = *(const bf16x8*)&Asl[b][(wm * 64 + mi * 16 + lr) * 32 + lg * 8];
    }
#pragma unroll
    for (int ni = 0; ni < 4; ++ni) {
      bfh[ni] = *(const bf16x8*)&Bsh[b][(wn * 64 + ni * 16 + lr) * 32 + lg * 8];
      bfl[ni] = *(const bf16x8*)&Bsl[b][(wn * 64 + ni * 16 + lr) * 32 + lg * 8];
    }
#pragma unroll
    for (int mi = 0; mi < 4; ++mi)
#pragma unroll
      for (int ni = 0; ni < 4; ++ni) {
        acc[mi][ni] = __builtin_amdgcn_mfma_f32_16x16x32_bf16(afh[mi], bfh[ni], acc[mi][ni], 0, 0, 0);
        acc[mi][ni] = __builtin_amdgcn_mfma_f32_16x16x32_bf16(afl[mi], bfh[ni], acc[mi][ni], 0, 0, 0);
        acc[mi][ni] = __builtin_amdgcn_mfma_f32_16x16x32_bf16(afh[mi], bfl[ni], acc[mi][ni], 0, 0, 0);
      }
    __builtin_amdgcn_sched_barrier(0);
    __builtin_amdgcn_s_barrier();
    __builtin_amdgcn_sched_barrier(0);
    if (t + 2 < nt) STAGE3(t + 2, b);
  }
#undef STAGE3

#pragma unroll
  for (int mi = 0; mi < 4; ++mi)
#pragma unroll
    for (int ni = 0; ni < 4; ++ni)
#pragma unroll
      for (int j = 0; j < 4; ++j) {
        long r = m0 + wm * 64 + mi * 16 + lg * 4 + j;
        long cc = n0 + wn * 64 + ni * 16 + lr;
        C[r * N + cc] = acc[mi][ni][j];
      }
}

// ---------------- K2 fragment-major index: K element (s, kvh, d) ----------------
__device__ __forceinline__ long k2idx(int kvh, int s, int d) {
  int ct = s >> 4;
  int lane = (((d & 31) >> 3) << 4) | (s & 15);
  return ((long)(kvh * 128 + ct) * 4 + (d >> 5)) * 512 + lane * 8 + (d & 7);
}

// ---------------- RoPE angle table ----------------
__global__ __launch_bounds__(256) void rope_table(float* __restrict__ ctab,
                                                  float* __restrict__ stab) {
  int idx = blockIdx.x * 256 + threadIdx.x;   // 2048*64
  if (idx >= 2048 * 64) return;
  int s = idx >> 6, d = idx & 63;
  float inv = powf(10000.0f, -(float)d * (1.0f / 64.0f));
  float ang = (float)s * inv;
  ctab[idx] = cosf(ang);
  stab[idx] = sinf(ang);
}

// ---------------- RoPE apply: fp32 -> Q (row-major hi/lo, pre-scaled), K (frag-major hi/lo) ----------------
__global__ __launch_bounds__(256) void rope_apply(const float* __restrict__ Qf,
                                                  const float* __restrict__ Kf,
                                                  const float* __restrict__ ctab,
                                                  const float* __restrict__ stab,
                                                  unsigned short* __restrict__ Qh,
                                                  unsigned short* __restrict__ Ql,
                                                  unsigned short* __restrict__ K2h,
                                                  unsigned short* __restrict__ K2l) {
  int t = blockIdx.x * 256 + threadIdx.x;     // 2048*40*16
  if (t >= 2048 * 40 * 16) return;
  int s = t / 640;
  int rem = t - s * 640;
  int hd = rem >> 4;
  int d4 = (rem & 15) * 4;
  float4 cv = *(const float4*)&ctab[s * 64 + d4];
  float4 sv = *(const float4*)&stab[s * 64 + d4];
  float cc[4] = {cv.x, cv.y, cv.z, cv.w};
  float ss[4] = {sv.x, sv.y, sv.z, sv.w};
  us4 h1, l1, h2, l2;
  if (hd < 32) {
    long row = (long)s * 4096 + hd * 128;
    float4 u1 = *(const float4*)&Qf[row + d4];
    float4 u2 = *(const float4*)&Qf[row + 64 + d4];
    float a1[4] = {u1.x, u1.y, u1.z, u1.w};
    float a2[4] = {u2.x, u2.y, u2.z, u2.w};
    const float scale = 0.08838834764831845f;  // 1/sqrt(128)
#pragma unroll
    for (int j = 0; j < 4; ++j) {
      float y1 = (a1[j] * cc[j] - a2[j] * ss[j]) * scale;
      float y2 = (a2[j] * cc[j] + a1[j] * ss[j]) * scale;
      h1[j] = f2bf(y1); l1[j] = f2bf(y1 - bf2f(h1[j]));
      h2[j] = f2bf(y2); l2[j] = f2bf(y2 - bf2f(h2[j]));
    }
    *(us4*)&Qh[row + d4] = h1;      *(us4*)&Ql[row + d4] = l1;
    *(us4*)&Qh[row + 64 + d4] = h2; *(us4*)&Ql[row + 64 + d4] = l2;
  } else {
    int kvh = hd - 32;
    long row = (long)s * 1024 + kvh * 128;
    float4 u1 = *(const float4*)&Kf[row + d4];
    float4 u2 = *(const float4*)&Kf[row + 64 + d4];
    float a1[4] = {u1.x, u1.y, u1.z, u1.w};
    float a2[4] = {u2.x, u2.y, u2.z, u2.w};
#pragma unroll
    for (int j = 0; j < 4; ++j) {
      float y1 = a1[j] * cc[j] - a2[j] * ss[j];
      float y2 = a2[j] * cc[j] + a1[j] * ss[j];
      h1[j] = f2bf(y1); l1[j] = f2bf(y1 - bf2f(h1[j]));
      h2[j] = f2bf(y2); l2[j] = f2bf(y2 - bf2f(h2[j]));
    }
    long i1 = k2idx(kvh, s, d4);
    long i2 = k2idx(kvh, s, d4 + 64);
    *(us4*)&K2h[i1] = h1; *(us4*)&K2l[i1] = l1;
    *(us4*)&K2h[i2] = h2; *(us4*)&K2l[i2] = l2;
  }
}

// ======== K1: cmax GEMM, 4-deep counted-vmcnt pipeline. ========
__global__ __launch_bounds__(256, 2) void cmax_gemm(const unsigned short* __restrict__ Qh,
                                                    const unsigned short* __restrict__ Ql,
                                                    const unsigned short* __restrict__ K2h,
                                                    const unsigned short* __restrict__ K2l,
                                                    float* __restrict__ cmaxg) {
  __shared__ __align__(16) unsigned short Ksh[4][4096];  // 4 x 8KB hi (32-tok panel)
  __shared__ __align__(16) unsigned short Ksl[4][4096];  // 4 x 8KB lo
  const int qp = 15 - (int)blockIdx.x;                   // heavy panels first
  const int h = blockIdx.y;
  const int kvh = h >> 2;
  const int q0 = qp * 128;
  const int tid = threadIdx.x;
  const int w = tid >> 6, l = tid & 63;
  const int lr = l & 15, lg = l >> 4;
  const int npan = 4 * (qp + 1);
  const float NEGINF = -__builtin_inff();

  bf16x8 qfh[2][4], qfl[2][4];
#pragma unroll
  for (int rg = 0; rg < 2; ++rg) {
    const unsigned short* qph = Qh + (long)(q0 + w * 32 + rg * 16 + lr) * 4096 + h * 128 + lg * 8;
    const unsigned short* qpl = Ql + (long)(q0 + w * 32 + rg * 16 + lr) * 4096 + h * 128 + lg * 8;
#pragma unroll
    for (int ks = 0; ks < 4; ++ks) {
      qfh[rg][ks] = *(const bf16x8*)(qph + ks * 32);
      qfl[rg][ks] = *(const bf16x8*)(qpl + ks * 32);
    }
  }

  const unsigned short* kbh = K2h + (long)kvh * 128 * 2048;
  const unsigned short* kbl = K2l + (long)kvh * 128 * 2048;

#define STAGE(kp, b)                                                       \
  {                                                                        \
    long off = (long)(kp) * 4096;                                          \
    _Pragma("unroll")                                                      \
    for (int i = 0; i < 2; ++i) {                                          \
      int cu = w * 128 + i * 64;                                           \
      gload16(kbh + off + (cu + l) * 8, &Ksh[b][cu * 8]);                  \
      gload16(kbl + off + (cu + l) * 8, &Ksl[b][cu * 8]);                  \
    }                                                                      \
  }

  STAGE(0, 0);
  if (1 < npan) STAGE(1, 1);
  if (2 < npan) STAGE(2, 2);

  for (int kp = 0; kp < npan; ++kp) {
    {
      int ahead = npan - 1 - kp; if (ahead > 2) ahead = 2;
      int st = kp; if (st > 3) st = 3;
      int tgt = 4 * ahead + 4 * st;
      if (tgt >= 20)      asm volatile("s_waitcnt vmcnt(20)" ::: "memory");
      else if (tgt >= 16) asm volatile("s_waitcnt vmcnt(16)" ::: "memory");
      else if (tgt >= 12) asm volatile("s_waitcnt vmcnt(12)" ::: "memory");
      else if (tgt >= 8)  asm volatile("s_waitcnt vmcnt(8)" ::: "memory");
      else                asm volatile("s_waitcnt vmcnt(0)" ::: "memory");
    }
    __builtin_amdgcn_s_barrier();
    __builtin_amdgcn_sched_barrier(0);
    if (kp + 3 < npan) STAGE(kp + 3, (kp + 3) & 3);
    const int b = kp & 3;
#pragma unroll
    for (int c2 = 0; c2 < 2; ++c2) {
      const int ct = kp * 2 + c2;
      bf16x8 kh[4], kl2[4];
#pragma unroll
      for (int ks = 0; ks < 4; ++ks) {
        kh[ks]  = *(const bf16x8*)&Ksh[b][(c2 * 4 + ks) * 512 + l * 8];
        kl2[ks] = *(const bf16x8*)&Ksl[b][(c2 * 4 + ks) * 512 + l * 8];
      }
#pragma unroll
      for (int rg = 0; rg < 2; ++rg) {
        f32x4 acc = {};
#pragma unroll
        for (int ks = 0; ks < 4; ++ks) {
          acc = __builtin_amdgcn_mfma_f32_16x16x32_bf16(kh[ks], qfh[rg][ks], acc, 0, 0, 0);
          acc = __builtin_amdgcn_mfma_f32_16x16x32_bf16(kh[ks], qfl[rg][ks], acc, 0, 0, 0);
          acc = __builtin_amdgcn_mfma_f32_16x16x32_bf16(kl2[ks], qfh[rg][ks], acc, 0, 0, 0);
        }
        const int rbase = q0 + w * 32 + rg * 16;
        float m;
        if (ct * 16 + 15 <= rbase) {
          m = fmaxf(fmaxf(acc[0], acc[1]), fmaxf(acc[2], acc[3]));
        } else {
          m = NEGINF;
#pragma unroll
          for (int j = 0; j < 4; ++j) {
            int tok = ct * 16 + lg * 4 + j;
            if (tok <= rbase + lr) m = fmaxf(m, acc[j]);
          }
        }
        m = fmaxf(m, __shfl_xor(m, 16));
        m = fmaxf(m, __shfl_xor(m, 32));
        if (l < 16) cmaxg[(long)(h * 128 + ct) * 2048 + rbase + l] = m;
      }
    }
  }
#undef STAGE
}

// ======== K2: per-row top-8 selection. block = (64-row group, head). ========
__global__ __launch_bounds__(256) void select_kernel(const float* __restrict__ cmaxg,
                                                     u64* __restrict__ selEg,
                                                     u64* __restrict__ selOg,
                                                     float* __restrict__ mxg) {
  __shared__ float Lc[128 * 65];                  // [ct][row], padded
  const int r0 = (int)blockIdx.x * 64;
  const int h = blockIdx.y;
  const int tid = threadIdx.x;
  const int w = tid >> 6, l = tid & 63;
  const float NEGINF = -__builtin_inff();

  for (int i = tid; i < 128 * 16; i += 256) {
    int ct = i >> 4, rq = (i & 15) * 4;
    float4 v = *(const float4*)&cmaxg[(long)(h * 128 + ct) * 2048 + r0 + rq];
    Lc[ct * 65 + rq]     = v.x;
    Lc[ct * 65 + rq + 1] = v.y;
    Lc[ct * 65 + rq + 2] = v.z;
    Lc[ct * 65 + rq + 3] = v.w;
  }
  __syncthreads();

  const int c0 = 2 * l, c1 = 2 * l + 1;
#pragma unroll 1
  for (int rs = 0; rs < 16; ++rs) {
    const int rloc = w * 16 + rs;
    const int qr = r0 + rloc;
    const int nctr = (qr >> 4) + 1;
    float v0 = (c0 < nctr) ? Lc[c0 * 65 + rloc] : NEGINF;
    float v1 = (c1 < nctr) ? Lc[c1 * 65 + rloc] : NEGINF;
    const float o0 = v0, o1 = v1;
    float T = NEGINF;
    for (int it = 0; it < 8; ++it) {
      float m = fmaxf(v0, v1);
#pragma unroll
      for (int o = 1; o < 64; o <<= 1) m = fmaxf(m, __shfl_xor(m, o));
      u64 bal = __ballot((v0 == m) || (v1 == m));
      int first = __ffsll(bal) - 1;
      if (l == first) { if (v0 == m) v0 = NEGINF; else v1 = NEGINF; }
      T = m;
    }
    bool okc0 = (c0 < nctr) && ((c0 < 8) || (o0 >= T));
    bool okc1 = (c1 < nctr) && ((c1 < 8) || (o1 >= T));
    u64 bE = __ballot(okc0);
    u64 bO = __ballot(okc1);
    bool al0 = (c0 < nctr) && (okc0 || (c0 * 16 + 15 > qr - 128));
    bool al1 = (c1 < nctr) && (okc1 || (c1 * 16 + 15 > qr - 128));
    float mv = fmaxf(al0 ? o0 : NEGINF, al1 ? o1 : NEGINF);
#pragma unroll
    for (int o = 1; o < 64; o <<= 1) mv = fmaxf(mv, __shfl_xor(mv, o));
    if (l == 0) {
      selEg[h * 2048 + qr] = bE;
      selOg[h * 2048 + qr] = bO;
      mxg[h * 2048 + qr] = mv;
    }
  }
}

// ---------------- P LDS swizzled index (per-wave slice): row, tok32 ----------------
__device__ __forceinline__ int pidx2(int r, int t) {
  return r * 32 + ((((t >> 3) ^ (r & 3)) << 3) | (t & 7));
}

// ======== K3: phase B — recompute selected chunks, exp, PV; K prefetched 1 pair ahead. ========
__global__ __launch_bounds__(256) void attnB(const unsigned short* __restrict__ Qh,
                                             const unsigned short* __restrict__ K2h,
                                             const unsigned short* __restrict__ V2,
                                             const u64* __restrict__ selEg,
                                             const u64* __restrict__ selOg,
                                             const float* __restrict__ mxg,
                                             unsigned short* __restrict__ AO) {
  __shared__ __align__(16) unsigned short Pls[4][512];
  __shared__ int clistS[4][128];

  const int qb = (int)gridDim.x - 1 - (int)blockIdx.x;   // heavy blocks first
  const int kvh = blockIdx.y;
  const int q0 = qb * 16;
  const int nct = qb + 1;
  const int tid = threadIdx.x;
  const int w = tid >> 6, l = tid & 63;
  const int lr = l & 15, lg = l >> 4;
  const int h = kvh * 4 + w;

  bf16x8 qfh[4];
  {
    const unsigned short* qph = Qh + (long)(q0 + lr) * 4096 + h * 128 + lg * 8;
#pragma unroll
    for (int ks = 0; ks < 4; ++ks) qfh[ks] = *(const bf16x8*)(qph + ks * 32);
  }

  u64 myE = selEg[h * 2048 + q0 + lr];
  u64 myO = selOg[h * 2048 + q0 + lr];
  float mymx = mxg[h * 2048 + q0 + lr];

  u64 uE = myE, uO = myO;
#pragma unroll
  for (int o = 1; o < 16; o <<= 1) {
    uE |= __shfl_xor(uE, o);
    uO |= __shfl_xor(uO, o);
  }
  float mxj[4];
  u64 selE[4], selO[4];
#pragma unroll
  for (int j = 0; j < 4; ++j) {
    mxj[j] = __shfl(mymx, lg * 4 + j);
    selE[j] = __shfl(myE, lg * 4 + j);
    selO[j] = __shfl(myO, lg * 4 + j);
  }

  unsigned short* Pw = Pls[w];
  int* cl = clistS[w];

  const int c0 = 2 * l, c1 = 2 * l + 1;
  bool s0ok = (c0 < nct) && (((uE >> l) & 1ull) || (c0 >= qb - 7));
  bool s1ok = (c1 < nct) && (((uO >> l) & 1ull) || (c1 >= qb - 7));
  u64 bA = __ballot(s0ok);
  u64 bB = __ballot(s1ok);
  const int cntA = __popcll(bA);
  const int nsel = cntA + __popcll(bB);
  if (s0ok) cl[__popcll(bA & ((1ull << l) - 1ull))] = c0;
  if (s1ok) cl[cntA + __popcll(bB & ((1ull << l) - 1ull))] = c1;

  const unsigned short* kbh = K2h + (long)kvh * 128 * 2048;

  f32x4 pacc[8] = {};
  float psum[4] = {0.f, 0.f, 0.f, 0.f};
  const int np = (nsel + 1) >> 1;

  // prefetch K fragments for pair 0
  bf16x8 kA[4], kB[4];
  {
    const int cA0 = cl[0];
    const int cB0 = (1 < nsel) ? cl[1] : cA0;
    const unsigned short* pA = kbh + (long)cA0 * 2048 + l * 8;
    const unsigned short* pB = kbh + (long)cB0 * 2048 + l * 8;
#pragma unroll
    for (int ks = 0; ks < 4; ++ks) {
      kA[ks] = *(const bf16x8*)(pA + ks * 512);
      kB[ks] = *(const bf16x8*)(pB + ks * 512);
    }
  }

  for (int pi = 0; pi < np; ++pi) {
    const int cA = cl[2 * pi];
    const int iB = 2 * pi + 1;
    const int cB = (iB < nsel) ? cl[iB] : cA;

    // V loads for this pair (early — hide under QK/exp)
    const int csel = (lg < 2) ? cA : cB;
    const unsigned short* vp = V2 + (long)(kvh * 128 + csel) * 2048 + ((lg & 1) * 16 + lr) * 8;
    bf16x8 vf[8];
#pragma unroll
    for (int dblk = 0; dblk < 8; ++dblk) vf[dblk] = *(const bf16x8*)(vp + dblk * 256);

    // prefetch next pair's K fragments (early — hide under exp/PV)
    bf16x8 nA[4], nB[4];
    {
      const int pin = (pi + 1 < np) ? pi + 1 : pi;
      const int cA1 = cl[2 * pin];
      const int iB1 = 2 * pin + 1;
      const int cB1 = (iB1 < nsel) ? cl[iB1] : cA1;
      const unsigned short* pA = kbh + (long)cA1 * 2048 + l * 8;
      const unsigned short* pB = kbh + (long)cB1 * 2048 + l * 8;
#pragma unroll
      for (int ks = 0; ks < 4; ++ks) {
        nA[ks] = *(const bf16x8*)(pA + ks * 512);
        nB[ks] = *(const bf16x8*)(pB + ks * 512);
      }
    }

#pragma unroll
    for (int half = 0; half < 2; ++half) {
      const int c = half ? cB : cA;
      const bool vslot = (2 * pi + half) < nsel;
      f32x4 acc = {};
#pragma unroll
      for (int ks = 0; ks < 4; ++ks) {
        bf16x8 kf = half ? kB[ks] : kA[ks];
        acc = __builtin_amdgcn_mfma_f32_16x16x32_bf16(qfh[ks], kf, acc, 0, 0, 0);
      }
#pragma unroll
      for (int j = 0; j < 4; ++j) {
        const int r = lg * 4 + j;
        const int qrr = q0 + r;
        const int tok = c * 16 + lr;
        u64 sm = (c & 1) ? selO[j] : selE[j];
        bool sel = (sm >> (c >> 1)) & 1ull;
        bool al = vslot && (tok <= qrr) && (sel || (tok > qrr - 128));
        float p = al ? __expf(acc[j] - mxj[j]) : 0.f;
        unsigned short pb = f2bf(p);
        psum[j] += bf2f(pb);
        Pw[pidx2(r, half * 16 + lr)] = pb;
      }
    }
    bf16x8 pa = *(const bf16x8*)&Pw[pidx2(lr, lg * 8)];
#pragma unroll
    for (int dblk = 0; dblk < 8; ++dblk)
      pacc[dblk] = __builtin_amdgcn_mfma_f32_16x16x32_bf16(pa, vf[dblk], pacc[dblk], 0, 0, 0);

#pragma unroll
    for (int ks = 0; ks < 4; ++ks) { kA[ks] = nA[ks]; kB[ks] = nB[ks]; }
  }

#pragma unroll
  for (int j = 0; j < 4; ++j) {
    float s = psum[j];
    s += __shfl_xor(s, 1); s += __shfl_xor(s, 2);
    s += __shfl_xor(s, 4); s += __shfl_xor(s, 8);
    const float rd = 1.0f / s;
    const int r = lg * 4 + j;
#pragma unroll
    for (int dblk = 0; dblk < 8; ++dblk)
      AO[(long)(q0 + r) * 4096 + h * 128 + dblk * 16 + lr] = f2bf(pacc[dblk][j] * rd);
  }
}

// ---------------- launch ----------------
extern "C" void kernel_launch(void* const* d_in, const int* in_sizes, int n_in,
                              void* d_out, int out_size, void* d_ws, size_t ws_size,
                              hipStream_t stream) {
  const float* hidden = (const float*)d_in[0];
  const float* wq = (const float*)d_in[1];
  const float* wk = (const float*)d_in[2];
  const float* wv = (const float*)d_in[3];
  const float* wo = (const float*)d_in[4];
  float* out = (float*)d_out;

  unsigned short* hb_hi = (unsigned short*)d_ws;          // [2048][4096]
  unsigned short* hb_lo = hb_hi + (size_t)2048 * 4096;
  unsigned short* wq_hi = hb_lo + (size_t)2048 * 4096;    // [4096][4096]
  unsigned short* wq_lo = wq_hi + (size_t)4096 * 4096;
  unsigned short* wk_hi = wq_lo + (size_t)4096 * 4096;    // [1024][4096]
  unsigned short* wk_lo = wk_hi + (size_t)1024 * 4096;
  unsigned short* wv_b  = wk_lo + (size_t)1024 * 4096;    // [1024][4096]
  unsigned short* wo_b  = wv_b  + (size_t)1024 * 4096;    // [4096][4096]
  float* Qf = (float*)(wo_b + (size_t)4096 * 4096);       // [2048][4096] fp32
  float* Kf = Qf + (size_t)2048 * 4096;                   // [2048][1024] fp32
  unsigned short* V2 = (unsigned short*)(Kf + (size_t)2048 * 1024);  // frag-major
  // aliases (stream-ordered lifetimes):
  unsigned short* Qhi = wq_hi;        // wq splits dead after Q-proj GEMM
  unsigned short* Qlo = wq_lo;
  unsigned short* K2h = wk_hi;        // wk splits dead after K-proj GEMM
  unsigned short* K2l = wk_lo;
  unsigned short* AO  = hb_hi;        // hidden splits dead after V GEMM
  float* ctab = (float*)wv_b;         // wv_b dead after V GEMM
  float* stab = ctab + 2048 * 64;
  float* cmaxg = Qf;                  // Qf dead after rope_apply
  u64* selEg = (u64*)Kf;              // Kf dead after rope_apply
  u64* selOg = selEg + 32 * 2048;
  float* mxg = (float*)(selOg + 32 * 2048);

  cvt_all<<<49152, 256, 0, stream>>>(hidden, wq, wk, wv, wo,
                                     hb_hi, hb_lo, wq_hi, wq_lo,
                                     wk_hi, wk_lo, wv_b, wo_b);

  gemm_bt3<<<dim3(32, 16), 256, 0, stream>>>(hb_hi, hb_lo, wq_hi, wq_lo, Qf, 2048, 4096, 4096);
  gemm_bt3<<<dim3(8, 16), 256, 0, stream>>>(hb_hi, hb_lo, wk_hi, wk_lo, Kf, 2048, 1024, 4096);
  gemm_bt<4><<<dim3(8, 16), 256, 0, stream>>>(hb_hi, wv_b, V2, 2048, 1024, 4096);

  rope_table<<<512, 256, 0, stream>>>(ctab, stab);
  rope_apply<<<5120, 256, 0, stream>>>(Qf, Kf, ctab, stab, Qhi, Qlo, K2h, K2l);

  cmax_gemm<<<dim3(16, 32), 256, 0, stream>>>(Qhi, Qlo, K2h, K2l, cmaxg);
  select_kernel<<<dim3(32, 32), 256, 0, stream>>>(cmaxg, selEg, selOg, mxg);
  attnB<<<dim3(128, 8), 256, 0, stream>>>(Qhi, K2h, V2, selEg, selOg, mxg, AO);

  gemm_bt<2><<<dim3(32, 16), 256, 0, stream>>>(AO, wo_b, out, 2048, 4096, 4096);
}

// Round 8
// 737.320 us; speedup vs baseline: 1.3076x; 1.0961x over previous
//
#include <hip/hip_runtime.h>
#include <math.h>

typedef __attribute__((ext_vector_type(4))) float f32x4;
typedef __attribute__((ext_vector_type(2))) float f32x2;
typedef __attribute__((ext_vector_type(8))) __bf16 bf16x8;
typedef __attribute__((ext_vector_type(4))) unsigned short us4;
typedef unsigned long long u64;

__device__ __forceinline__ unsigned short f2bf(float f) {
  unsigned int u = __float_as_uint(f);
  u += 0x7fffu + ((u >> 16) & 1u);            // RNE
  return (unsigned short)(u >> 16);
}
__device__ __forceinline__ float bf2f(unsigned short h) {
  return __uint_as_float(((unsigned int)h) << 16);
}

__device__ __forceinline__ void gload16(const void* g, void* l) {
  __builtin_amdgcn_global_load_lds(
      (__attribute__((address_space(1))) void*)g,
      (__attribute__((address_space(3))) void*)l, 16, 0, 0);
}

// ---------------- fused fp32 -> bf16 conversions (all 5 inputs, one kernel) ----------------
__device__ __forceinline__ void split1(const float* __restrict__ in,
                                       unsigned short* __restrict__ hi,
                                       unsigned short* __restrict__ lo, int i) {
  float4 v = ((const float4*)in)[i];
  us4 h, l;
  float vv[4] = {v.x, v.y, v.z, v.w};
#pragma unroll
  for (int j = 0; j < 4; ++j) {
    unsigned short hh = f2bf(vv[j]);
    h[j] = hh;
    l[j] = f2bf(vv[j] - bf2f(hh));
  }
  ((us4*)hi)[i] = h;
  ((us4*)lo)[i] = l;
}
__device__ __forceinline__ void plain1(const float* __restrict__ in,
                                       unsigned short* __restrict__ out, int i) {
  float4 v = ((const float4*)in)[i];
  us4 o;
  o[0] = f2bf(v.x); o[1] = f2bf(v.y); o[2] = f2bf(v.z); o[3] = f2bf(v.w);
  ((us4*)out)[i] = o;
}

__global__ __launch_bounds__(256) void cvt_all(const float* __restrict__ hidden,
                                               const float* __restrict__ wq,
                                               const float* __restrict__ wk,
                                               const float* __restrict__ wv,
                                               const float* __restrict__ wo,
                                               unsigned short* __restrict__ hb_hi,
                                               unsigned short* __restrict__ hb_lo,
                                               unsigned short* __restrict__ wq_hi,
                                               unsigned short* __restrict__ wq_lo,
                                               unsigned short* __restrict__ wk_hi,
                                               unsigned short* __restrict__ wk_lo,
                                               unsigned short* __restrict__ wv_b,
                                               unsigned short* __restrict__ wo_b) {
  int i = blockIdx.x * 256 + threadIdx.x;
  if (i < 2097152)       split1(hidden, hb_hi, hb_lo, i);
  else if (i < 6291456)  split1(wq, wq_hi, wq_lo, i - 2097152);
  else if (i < 7340032)  split1(wk, wk_hi, wk_lo, i - 6291456);
  else if (i < 8388608)  plain1(wv, wv_b, i - 7340032);
  else if (i < 12582912) plain1(wo, wo_b, i - 8388608);
}

// ======== fused QKV projection GEMM ========
// blocks [0,128): K-proj (3-term split, C=Kf fp32, N=1024)
// blocks [128,256): V-proj (1-term bf16, C=V2 fragment-major, N=1024)
// blocks [256,768): Q-proj (3-term split, C=Qf fp32, N=4096)
// Per-block bodies bit-identical to round-7 gemm_bt3 / gemm_bt<4>.
__global__ __launch_bounds__(256) void qkv_gemm(const unsigned short* __restrict__ Ahg,
                                                const unsigned short* __restrict__ Alg,
                                                const unsigned short* __restrict__ wq_hi,
                                                const unsigned short* __restrict__ wq_lo,
                                                const unsigned short* __restrict__ wk_hi,
                                                const unsigned short* __restrict__ wk_lo,
                                                const unsigned short* __restrict__ wv_b,
                                                float* __restrict__ Qf,
                                                float* __restrict__ Kf,
                                                unsigned short* __restrict__ V2) {
  __shared__ __align__(16) unsigned short Ash[2][4096];
  __shared__ __align__(16) unsigned short Asl[2][4096];
  __shared__ __align__(16) unsigned short Bsh[2][4096];
  __shared__ __align__(16) unsigned short Bsl[2][4096];
  const int bid = blockIdx.x;
  const int tid = threadIdx.x;
  const int w = tid >> 6, l = tid & 63;
  const int wm = w >> 1, wn = w & 1;
  const int lr = l & 15, lg = l >> 4;
  const int K = 4096;
  const int nt = K >> 5;   // 128

  if (bid >= 128 && bid < 256) {
    // ---------------- V-proj: 1-term bf16, V2 fragment-major store ----------------
    const int b3 = bid - 128;
    const long m0 = (long)(b3 >> 3) * 128, n0 = (long)(b3 & 7) * 128;
    f32x4 acc[4][4] = {};
    const int c0 = w * 128 + l;
    const int c1 = c0 + 64;
    const unsigned short* gA0 = Ahg + (m0 + (c0 >> 2)) * K + (c0 & 3) * 8;
    const unsigned short* gA1 = Ahg + (m0 + (c1 >> 2)) * K + (c1 & 3) * 8;
    const unsigned short* gB0 = wv_b + (n0 + (c0 >> 2)) * K + (c0 & 3) * 8;
    const unsigned short* gB1 = wv_b + (n0 + (c1 >> 2)) * K + (c1 & 3) * 8;

#define STAGE1(t, b)                                   \
  {                                                    \
    long kt = (long)(t) * 32;                          \
    gload16(gA0 + kt, &Ash[b][w * 1024]);              \
    gload16(gA1 + kt, &Ash[b][w * 1024 + 512]);        \
    gload16(gB0 + kt, &Bsh[b][w * 1024]);              \
    gload16(gB1 + kt, &Bsh[b][w * 1024 + 512]);        \
  }
    STAGE1(0, 0);
    STAGE1(1, 1);
    for (int t = 0; t < nt; ++t) {
      if (t + 1 < nt) asm volatile("s_waitcnt vmcnt(4)" ::: "memory");
      else            asm volatile("s_waitcnt vmcnt(0)" ::: "memory");
      __builtin_amdgcn_s_barrier();
      __builtin_amdgcn_sched_barrier(0);
      const int b = t & 1;
      bf16x8 af[4], bfr[4];
#pragma unroll
      for (int mi = 0; mi < 4; ++mi)
        af[mi] = *(const bf16x8*)&Ash[b][(wm * 64 + mi * 16 + lr) * 32 + lg * 8];
#pragma unroll
      for (int ni = 0; ni < 4; ++ni)
        bfr[ni] = *(const bf16x8*)&Bsh[b][(wn * 64 + ni * 16 + lr) * 32 + lg * 8];
#pragma unroll
      for (int mi = 0; mi < 4; ++mi)
#pragma unroll
        for (int ni = 0; ni < 4; ++ni)
          acc[mi][ni] = __builtin_amdgcn_mfma_f32_16x16x32_bf16(af[mi], bfr[ni], acc[mi][ni], 0, 0, 0);
      __builtin_amdgcn_sched_barrier(0);
      __builtin_amdgcn_s_barrier();
      __builtin_amdgcn_sched_barrier(0);
      if (t + 2 < nt) STAGE1(t + 2, b);
    }
#undef STAGE1
#pragma unroll
    for (int mi = 0; mi < 4; ++mi)
#pragma unroll
      for (int ni = 0; ni < 4; ++ni)
#pragma unroll
        for (int j = 0; j < 4; ++j) {
          long r = m0 + wm * 64 + mi * 16 + lg * 4 + j;
          long cc = n0 + wn * 64 + ni * 16 + lr;
          int kvh = (int)(cc >> 7), d = (int)(cc & 127);
          int c = (int)(r >> 4), t2 = (int)(r & 15);
          long idx = ((long)(kvh * 128 + c) * 8 + (d >> 4)) * 256 + ((t2 >> 3) * 16 + (d & 15)) * 8 + (t2 & 7);
          V2[idx] = f2bf(acc[mi][ni][j]);
        }
    return;
  }

  // ---------------- Q-proj / K-proj: 3-term split GEMM, fp32 store ----------------
  const unsigned short *Bh, *Bl;
  float* C;
  int N;
  long m0, n0;
  if (bid < 128) {
    m0 = (long)(bid >> 3) * 128; n0 = (long)(bid & 7) * 128;
    Bh = wk_hi; Bl = wk_lo; C = Kf; N = 1024;
  } else {
    const int b2 = bid - 256;
    m0 = (long)(b2 >> 5) * 128; n0 = (long)(b2 & 31) * 128;
    Bh = wq_hi; Bl = wq_lo; C = Qf; N = 4096;
  }

  f32x4 acc[4][4] = {};
  const int c0 = w * 128 + l;
  const int c1 = c0 + 64;
  const long oA0 = (m0 + (c0 >> 2)) * K + (c0 & 3) * 8;
  const long oA1 = (m0 + (c1 >> 2)) * K + (c1 & 3) * 8;
  const long oB0 = (n0 + (c0 >> 2)) * K + (c0 & 3) * 8;
  const long oB1 = (n0 + (c1 >> 2)) * K + (c1 & 3) * 8;

#define STAGE3(t, b)                                        \
  {                                                         \
    long kt = (long)(t) * 32;                               \
    gload16(Ahg + oA0 + kt, &Ash[b][w * 1024]);             \
    gload16(Ahg + oA1 + kt, &Ash[b][w * 1024 + 512]);       \
    gload16(Alg + oA0 + kt, &Asl[b][w * 1024]);             \
    gload16(Alg + oA1 + kt, &Asl[b][w * 1024 + 512]);       \
    gload16(Bh + oB0 + kt, &Bsh[b][w * 1024]);              \
    gload16(Bh + oB1 + kt, &Bsh[b][w * 1024 + 512]);        \
    gload16(Bl + oB0 + kt, &Bsl[b][w * 1024]);              \
    gload16(Bl + oB1 + kt, &Bsl[b][w * 1024 + 512]);        \
  }
  STAGE3(0, 0);
  STAGE3(1, 1);
  for (int t = 0; t < nt; ++t) {
    if (t + 1 < nt) asm volatile("s_waitcnt vmcnt(8)" ::: "memory");
    else            asm volatile("s_waitcnt vmcnt(0)" ::: "memory");
    __builtin_amdgcn_s_barrier();
    __builtin_amdgcn_sched_barrier(0);
    const int b = t & 1;
    bf16x8 afh[4], afl[4], bfh[4], bfl[4];
#pragma unroll
    for (int mi = 0; mi < 4; ++mi) {
      afh[mi] = *(const bf16x8*)&Ash[b][(wm * 64 + mi * 16 + lr) * 32 + lg * 8];
      afl[mi] = *(const bf16x8*)&Asl[b][(wm * 64 + mi * 16 + lr) * 32 + lg * 8];
    }
#pragma unroll
    for (int ni = 0; ni < 4; ++ni) {
      bfh[ni] = *(const bf16x8*)&Bsh[b][(wn * 64 + ni * 16 + lr) * 32 + lg * 8];
      bfl[ni] = *(const bf16x8*)&Bsl[b][(wn * 64 + ni * 16 + lr) * 32 + lg * 8];
    }
#pragma unroll
    for (int mi = 0; mi < 4; ++mi)
#pragma unroll
      for (int ni = 0; ni < 4; ++ni) {
        acc[mi][ni] = __builtin_amdgcn_mfma_f32_16x16x32_bf16(afh[mi], bfh[ni], acc[mi][ni], 0, 0, 0);
        acc[mi][ni] = __builtin_amdgcn_mfma_f32_16x16x32_bf16(afl[mi], bfh[ni], acc[mi][ni], 0, 0, 0);
        acc[mi][ni] = __builtin_amdgcn_mfma_f32_16x16x32_bf16(afh[mi], bfl[ni], acc[mi][ni], 0, 0, 0);
      }
    __builtin_amdgcn_sched_barrier(0);
    __builtin_amdgcn_s_barrier();
    __builtin_amdgcn_sched_barrier(0);
    if (t + 2 < nt) STAGE3(t + 2, b);
  }
#undef STAGE3

#pragma unroll
  for (int mi = 0; mi < 4; ++mi)
#pragma unroll
    for (int ni = 0; ni < 4; ++ni)
#pragma unroll
      for (int j = 0; j < 4; ++j) {
        long r = m0 + wm * 64 + mi * 16 + lg * 4 + j;
        long cc = n0 + wn * 64 + ni * 16 + lr;
        C[r * N + cc] = acc[mi][ni][j];
      }
}

// ---------------- GEMM: C = A * B^T (O-proj), counted-vmcnt double-buffered ----------------
template<int SM>
__global__ __launch_bounds__(256) void gemm_bt(const unsigned short* __restrict__ A,
                                               const unsigned short* __restrict__ B,
                                               void* __restrict__ C,
                                               int M, int N, int K) {
  __shared__ __align__(16) unsigned short As[2][4096];
  __shared__ __align__(16) unsigned short Bs[2][4096];
  const int tid = threadIdx.x;
  const int w = tid >> 6, l = tid & 63;
  const int wm = w >> 1, wn = w & 1;
  const int lr = l & 15, lg = l >> 4;
  const long m0 = (long)blockIdx.y * 128, n0 = (long)blockIdx.x * 128;

  f32x4 acc[4][4] = {};

  const int c0 = w * 128 + l;
  const int c1 = c0 + 64;
  const unsigned short* gA0 = A + (m0 + (c0 >> 2)) * K + (c0 & 3) * 8;
  const unsigned short* gA1 = A + (m0 + (c1 >> 2)) * K + (c1 & 3) * 8;
  const unsigned short* gB0 = B + (n0 + (c0 >> 2)) * K + (c0 & 3) * 8;
  const unsigned short* gB1 = B + (n0 + (c1 >> 2)) * K + (c1 & 3) * 8;

#define STAGE1(t, b)                                   \
  {                                                    \
    long kt = (long)(t) * 32;                          \
    gload16(gA0 + kt, &As[b][w * 1024]);               \
    gload16(gA1 + kt, &As[b][w * 1024 + 512]);         \
    gload16(gB0 + kt, &Bs[b][w * 1024]);               \
    gload16(gB1 + kt, &Bs[b][w * 1024 + 512]);         \
  }

  const int nt = K >> 5;
  STAGE1(0, 0);
  if (nt > 1) STAGE1(1, 1);

  for (int t = 0; t < nt; ++t) {
    if (t + 1 < nt) asm volatile("s_waitcnt vmcnt(4)" ::: "memory");
    else            asm volatile("s_waitcnt vmcnt(0)" ::: "memory");
    __builtin_amdgcn_s_barrier();
    __builtin_amdgcn_sched_barrier(0);
    const int b = t & 1;
    bf16x8 af[4], bfr[4];
#pragma unroll
    for (int mi = 0; mi < 4; ++mi)
      af[mi] = *(const bf16x8*)&As[b][(wm * 64 + mi * 16 + lr) * 32 + lg * 8];
#pragma unroll
    for (int ni = 0; ni < 4; ++ni)
      bfr[ni] = *(const bf16x8*)&Bs[b][(wn * 64 + ni * 16 + lr) * 32 + lg * 8];
#pragma unroll
    for (int mi = 0; mi < 4; ++mi)
#pragma unroll
      for (int ni = 0; ni < 4; ++ni)
        acc[mi][ni] = __builtin_amdgcn_mfma_f32_16x16x32_bf16(af[mi], bfr[ni], acc[mi][ni], 0, 0, 0);
    __builtin_amdgcn_sched_barrier(0);
    __builtin_amdgcn_s_barrier();
    __builtin_amdgcn_sched_barrier(0);
    if (t + 2 < nt) STAGE1(t + 2, b);
  }
#undef STAGE1

#pragma unroll
  for (int mi = 0; mi < 4; ++mi)
#pragma unroll
    for (int ni = 0; ni < 4; ++ni)
#pragma unroll
      for (int j = 0; j < 4; ++j) {
        long r = m0 + wm * 64 + mi * 16 + lg * 4 + j;
        long cc = n0 + wn * 64 + ni * 16 + lr;
        ((float*)C)[r * N + cc] = acc[mi][ni][j];
      }
}

// ---------------- K2 fragment-major index: K element (s, kvh, d) ----------------
__device__ __forceinline__ long k2idx(int kvh, int s, int d) {
  int ct = s >> 4;
  int lane = (((d & 31) >> 3) << 4) | (s & 15);
  return ((long)(kvh * 128 + ct) * 4 + (d >> 5)) * 512 + lane * 8 + (d & 7);
}

// ---------------- RoPE angle table ----------------
__global__ __launch_bounds__(256) void rope_table(float* __restrict__ ctab,
                                                  float* __restrict__ stab) {
  int idx = blockIdx.x * 256 + threadIdx.x;   // 2048*64
  if (idx >= 2048 * 64) return;
  int s = idx >> 6, d = idx & 63;
  float inv = powf(10000.0f, -(float)d * (1.0f / 64.0f));
  float ang = (float)s * inv;
  ctab[idx] = cosf(ang);
  stab[idx] = sinf(ang);
}

// ---------------- RoPE apply: fp32 -> Q (row-major hi/lo, pre-scaled), K (frag-major hi/lo) ----------------
__global__ __launch_bounds__(256) void rope_apply(const float* __restrict__ Qf,
                                                  const float* __restrict__ Kf,
                                                  const float* __restrict__ ctab,
                                                  const float* __restrict__ stab,
                                                  unsigned short* __restrict__ Qh,
                                                  unsigned short* __restrict__ Ql,
                                                  unsigned short* __restrict__ K2h,
                                                  unsigned short* __restrict__ K2l) {
  int t = blockIdx.x * 256 + threadIdx.x;     // 2048*40*16
  if (t >= 2048 * 40 * 16) return;
  int s = t / 640;
  int rem = t - s * 640;
  int hd = rem >> 4;
  int d4 = (rem & 15) * 4;
  float4 cv = *(const float4*)&ctab[s * 64 + d4];
  float4 sv = *(const float4*)&stab[s * 64 + d4];
  float cc[4] = {cv.x, cv.y, cv.z, cv.w};
  float ss[4] = {sv.x, sv.y, sv.z, sv.w};
  us4 h1, l1, h2, l2;
  if (hd < 32) {
    long row = (long)s * 4096 + hd * 128;
    float4 u1 = *(const float4*)&Qf[row + d4];
    float4 u2 = *(const float4*)&Qf[row + 64 + d4];
    float a1[4] = {u1.x, u1.y, u1.z, u1.w};
    float a2[4] = {u2.x, u2.y, u2.z, u2.w};
    const float scale = 0.08838834764831845f;  // 1/sqrt(128)
#pragma unroll
    for (int j = 0; j < 4; ++j) {
      float y1 = (a1[j] * cc[j] - a2[j] * ss[j]) * scale;
      float y2 = (a2[j] * cc[j] + a1[j] * ss[j]) * scale;
      h1[j] = f2bf(y1); l1[j] = f2bf(y1 - bf2f(h1[j]));
      h2[j] = f2bf(y2); l2[j] = f2bf(y2 - bf2f(h2[j]));
    }
    *(us4*)&Qh[row + d4] = h1;      *(us4*)&Ql[row + d4] = l1;
    *(us4*)&Qh[row + 64 + d4] = h2; *(us4*)&Ql[row + 64 + d4] = l2;
  } else {
    int kvh = hd - 32;
    long row = (long)s * 1024 + kvh * 128;
    float4 u1 = *(const float4*)&Kf[row + d4];
    float4 u2 = *(const float4*)&Kf[row + 64 + d4];
    float a1[4] = {u1.x, u1.y, u1.z, u1.w};
    float a2[4] = {u2.x, u2.y, u2.z, u2.w};
#pragma unroll
    for (int j = 0; j < 4; ++j) {
      float y1 = a1[j] * cc[j] - a2[j] * ss[j];
      float y2 = a2[j] * cc[j] + a1[j] * ss[j];
      h1[j] = f2bf(y1); l1[j] = f2bf(y1 - bf2f(h1[j]));
      h2[j] = f2bf(y2); l2[j] = f2bf(y2 - bf2f(h2[j]));
    }
    long i1 = k2idx(kvh, s, d4);
    long i2 = k2idx(kvh, s, d4 + 64);
    *(us4*)&K2h[i1] = h1; *(us4*)&K2l[i1] = l1;
    *(us4*)&K2h[i2] = h2; *(us4*)&K2l[i2] = l2;
  }
}

// ======== K1: cmax GEMM, 4-deep counted-vmcnt pipeline. ========
__global__ __launch_bounds__(256, 2) void cmax_gemm(const unsigned short* __restrict__ Qh,
                                                    const unsigned short* __restrict__ Ql,
                                                    const unsigned short* __restrict__ K2h,
                                                    const unsigned short* __restrict__ K2l,
                                                    float* __restrict__ cmaxg) {
  __shared__ __align__(16) unsigned short Ksh[4][4096];  // 4 x 8KB hi (32-tok panel)
  __shared__ __align__(16) unsigned short Ksl[4][4096];  // 4 x 8KB lo
  const int qp = 15 - (int)blockIdx.x;                   // heavy panels first
  const int h = blockIdx.y;
  const int kvh = h >> 2;
  const int q0 = qp * 128;
  const int tid = threadIdx.x;
  const int w = tid >> 6, l = tid & 63;
  const int lr = l & 15, lg = l >> 4;
  const int npan = 4 * (qp + 1);
  const float NEGINF = -__builtin_inff();

  bf16x8 qfh[2][4], qfl[2][4];
#pragma unroll
  for (int rg = 0; rg < 2; ++rg) {
    const unsigned short* qph = Qh + (long)(q0 + w * 32 + rg * 16 + lr) * 4096 + h * 128 + lg * 8;
    const unsigned short* qpl = Ql + (long)(q0 + w * 32 + rg * 16 + lr) * 4096 + h * 128 + lg * 8;
#pragma unroll
    for (int ks = 0; ks < 4; ++ks) {
      qfh[rg][ks] = *(const bf16x8*)(qph + ks * 32);
      qfl[rg][ks] = *(const bf16x8*)(qpl + ks * 32);
    }
  }

  const unsigned short* kbh = K2h + (long)kvh * 128 * 2048;
  const unsigned short* kbl = K2l + (long)kvh * 128 * 2048;

#define STAGE(kp, b)                                                       \
  {                                                                        \
    long off = (long)(kp) * 4096;                                          \
    _Pragma("unroll")                                                      \
    for (int i = 0; i < 2; ++i) {                                          \
      int cu = w * 128 + i * 64;                                           \
      gload16(kbh + off + (cu + l) * 8, &Ksh[b][cu * 8]);                  \
      gload16(kbl + off + (cu + l) * 8, &Ksl[b][cu * 8]);                  \
    }                                                                      \
  }

  STAGE(0, 0);
  if (1 < npan) STAGE(1, 1);
  if (2 < npan) STAGE(2, 2);

  for (int kp = 0; kp < npan; ++kp) {
    {
      int ahead = npan - 1 - kp; if (ahead > 2) ahead = 2;
      int st = kp; if (st > 3) st = 3;
      int tgt = 4 * ahead + 4 * st;
      if (tgt >= 20)      asm volatile("s_waitcnt vmcnt(20)" ::: "memory");
      else if (tgt >= 16) asm volatile("s_waitcnt vmcnt(16)" ::: "memory");
      else if (tgt >= 12) asm volatile("s_waitcnt vmcnt(12)" ::: "memory");
      else if (tgt >= 8)  asm volatile("s_waitcnt vmcnt(8)" ::: "memory");
      else                asm volatile("s_waitcnt vmcnt(0)" ::: "memory");
    }
    __builtin_amdgcn_s_barrier();
    __builtin_amdgcn_sched_barrier(0);
    if (kp + 3 < npan) STAGE(kp + 3, (kp + 3) & 3);
    const int b = kp & 3;
#pragma unroll
    for (int c2 = 0; c2 < 2; ++c2) {
      const int ct = kp * 2 + c2;
      bf16x8 kh[4], kl2[4];
#pragma unroll
      for (int ks = 0; ks < 4; ++ks) {
        kh[ks]  = *(const bf16x8*)&Ksh[b][(c2 * 4 + ks) * 512 + l * 8];
        kl2[ks] = *(const bf16x8*)&Ksl[b][(c2 * 4 + ks) * 512 + l * 8];
      }
#pragma unroll
      for (int rg = 0; rg < 2; ++rg) {
        f32x4 acc = {};
#pragma unroll
        for (int ks = 0; ks < 4; ++ks) {
          acc = __builtin_amdgcn_mfma_f32_16x16x32_bf16(kh[ks], qfh[rg][ks], acc, 0, 0, 0);
          acc = __builtin_amdgcn_mfma_f32_16x16x32_bf16(kh[ks], qfl[rg][ks], acc, 0, 0, 0);
          acc = __builtin_amdgcn_mfma_f32_16x16x32_bf16(kl2[ks], qfh[rg][ks], acc, 0, 0, 0);
        }
        const int rbase = q0 + w * 32 + rg * 16;
        float m;
        if (ct * 16 + 15 <= rbase) {
          m = fmaxf(fmaxf(acc[0], acc[1]), fmaxf(acc[2], acc[3]));
        } else {
          m = NEGINF;
#pragma unroll
          for (int j = 0; j < 4; ++j) {
            int tok = ct * 16 + lg * 4 + j;
            if (tok <= rbase + lr) m = fmaxf(m, acc[j]);
          }
        }
        m = fmaxf(m, __shfl_xor(m, 16));
        m = fmaxf(m, __shfl_xor(m, 32));
        if (l < 16) cmaxg[(long)(h * 128 + ct) * 2048 + rbase + l] = m;
      }
    }
  }
#undef STAGE
}

// ======== K2: per-row top-8 selection. block = (64-row group, head). ========
__global__ __launch_bounds__(256) void select_kernel(const float* __restrict__ cmaxg,
                                                     u64* __restrict__ selEg,
                                                     u64* __restrict__ selOg,
                                                     float* __restrict__ mxg) {
  __shared__ float Lc[128 * 65];                  // [ct][row], padded
  const int r0 = (int)blockIdx.x * 64;
  const int h = blockIdx.y;
  const int tid = threadIdx.x;
  const int w = tid >> 6, l = tid & 63;
  const float NEGINF = -__builtin_inff();

  for (int i = tid; i < 128 * 16; i += 256) {
    int ct = i >> 4, rq = (i & 15) * 4;
    float4 v = *(const float4*)&cmaxg[(long)(h * 128 + ct) * 2048 + r0 + rq];
    Lc[ct * 65 + rq]     = v.x;
    Lc[ct * 65 + rq + 1] = v.y;
    Lc[ct * 65 + rq + 2] = v.z;
    Lc[ct * 65 + rq + 3] = v.w;
  }
  __syncthreads();

  const int c0 = 2 * l, c1 = 2 * l + 1;
#pragma unroll 1
  for (int rs = 0; rs < 16; ++rs) {
    const int rloc = w * 16 + rs;
    const int qr = r0 + rloc;
    const int nctr = (qr >> 4) + 1;
    float v0 = (c0 < nctr) ? Lc[c0 * 65 + rloc] : NEGINF;
    float v1 = (c1 < nctr) ? Lc[c1 * 65 + rloc] : NEGINF;
    const float o0 = v0, o1 = v1;
    float T = NEGINF;
    for (int it = 0; it < 8; ++it) {
      float m = fmaxf(v0, v1);
#pragma unroll
      for (int o = 1; o < 64; o <<= 1) m = fmaxf(m, __shfl_xor(m, o));
      u64 bal = __ballot((v0 == m) || (v1 == m));
      int first = __ffsll(bal) - 1;
      if (l == first) { if (v0 == m) v0 = NEGINF; else v1 = NEGINF; }
      T = m;
    }
    bool okc0 = (c0 < nctr) && ((c0 < 8) || (o0 >= T));
    bool okc1 = (c1 < nctr) && ((c1 < 8) || (o1 >= T));
    u64 bE = __ballot(okc0);
    u64 bO = __ballot(okc1);
    bool al0 = (c0 < nctr) && (okc0 || (c0 * 16 + 15 > qr - 128));
    bool al1 = (c1 < nctr) && (okc1 || (c1 * 16 + 15 > qr - 128));
    float mv = fmaxf(al0 ? o0 : NEGINF, al1 ? o1 : NEGINF);
#pragma unroll
    for (int o = 1; o < 64; o <<= 1) mv = fmaxf(mv, __shfl_xor(mv, o));
    if (l == 0) {
      selEg[h * 2048 + qr] = bE;
      selOg[h * 2048 + qr] = bO;
      mxg[h * 2048 + qr] = mv;
    }
  }
}

// ---------------- P LDS swizzled index (per-wave slice): row, tok32 ----------------
__device__ __forceinline__ int pidx2(int r, int t) {
  return r * 32 + ((((t >> 3) ^ (r & 3)) << 3) | (t & 7));
}

// ======== K3: phase B — recompute selected chunks, exp, PV; K prefetched 1 pair ahead. ========
__global__ __launch_bounds__(256) void attnB(const unsigned short* __restrict__ Qh,
                                             const unsigned short* __restrict__ K2h,
                                             const unsigned short* __restrict__ V2,
                                             const u64* __restrict__ selEg,
                                             const u64* __restrict__ selOg,
                                             const float* __restrict__ mxg,
                                             unsigned short* __restrict__ AO) {
  __shared__ __align__(16) unsigned short Pls[4][512];
  __shared__ int clistS[4][128];

  const int qb = (int)gridDim.x - 1 - (int)blockIdx.x;   // heavy blocks first
  const int kvh = blockIdx.y;
  const int q0 = qb * 16;
  const int nct = qb + 1;
  const int tid = threadIdx.x;
  const int w = tid >> 6, l = tid & 63;
  const int lr = l & 15, lg = l >> 4;
  const int h = kvh * 4 + w;

  bf16x8 qfh[4];
  {
    const unsigned short* qph = Qh + (long)(q0 + lr) * 4096 + h * 128 + lg * 8;
#pragma unroll
    for (int ks = 0; ks < 4; ++ks) qfh[ks] = *(const bf16x8*)(qph + ks * 32);
  }

  u64 myE = selEg[h * 2048 + q0 + lr];
  u64 myO = selOg[h * 2048 + q0 + lr];
  float mymx = mxg[h * 2048 + q0 + lr];

  u64 uE = myE, uO = myO;
#pragma unroll
  for (int o = 1; o < 16; o <<= 1) {
    uE |= __shfl_xor(uE, o);
    uO |= __shfl_xor(uO, o);
  }
  float mxj[4];
  u64 selE[4], selO[4];
#pragma unroll
  for (int j = 0; j < 4; ++j) {
    mxj[j] = __shfl(mymx, lg * 4 + j);
    selE[j] = __shfl(myE, lg * 4 + j);
    selO[j] = __shfl(myO, lg * 4 + j);
  }

  unsigned short* Pw = Pls[w];
  int* cl = clistS[w];

  const int c0 = 2 * l, c1 = 2 * l + 1;
  bool s0ok = (c0 < nct) && (((uE >> l) & 1ull) || (c0 >= qb - 7));
  bool s1ok = (c1 < nct) && (((uO >> l) & 1ull) || (c1 >= qb - 7));
  u64 bA = __ballot(s0ok);
  u64 bB = __ballot(s1ok);
  const int cntA = __popcll(bA);
  const int nsel = cntA + __popcll(bB);
  if (s0ok) cl[__popcll(bA & ((1ull << l) - 1ull))] = c0;
  if (s1ok) cl[cntA + __popcll(bB & ((1ull << l) - 1ull))] = c1;

  const unsigned short* kbh = K2h + (long)kvh * 128 * 2048;

  f32x4 pacc[8] = {};
  float psum[4] = {0.f, 0.f, 0.f, 0.f};
  const int np = (nsel + 1) >> 1;

  bf16x8 kA[4], kB[4];
  {
    const int cA0 = cl[0];
    const int cB0 = (1 < nsel) ? cl[1] : cA0;
    const unsigned short* pA = kbh + (long)cA0 * 2048 + l * 8;
    const unsigned short* pB = kbh + (long)cB0 * 2048 + l * 8;
#pragma unroll
    for (int ks = 0; ks < 4; ++ks) {
      kA[ks] = *(const bf16x8*)(pA + ks * 512);
      kB[ks] = *(const bf16x8*)(pB + ks * 512);
    }
  }

  for (int pi = 0; pi < np; ++pi) {
    const int cA = cl[2 * pi];
    const int iB = 2 * pi + 1;
    const int cB = (iB < nsel) ? cl[iB] : cA;

    const int csel = (lg < 2) ? cA : cB;
    const unsigned short* vp = V2 + (long)(kvh * 128 + csel) * 2048 + ((lg & 1) * 16 + lr) * 8;
    bf16x8 vf[8];
#pragma unroll
    for (int dblk = 0; dblk < 8; ++dblk) vf[dblk] = *(const bf16x8*)(vp + dblk * 256);

    bf16x8 nA[4], nB[4];
    {
      const int pin = (pi + 1 < np) ? pi + 1 : pi;
      const int cA1 = cl[2 * pin];
      const int iB1 = 2 * pin + 1;
      const int cB1 = (iB1 < nsel) ? cl[iB1] : cA1;
      const unsigned short* pA = kbh + (long)cA1 * 2048 + l * 8;
      const unsigned short* pB = kbh + (long)cB1 * 2048 + l * 8;
#pragma unroll
      for (int ks = 0; ks < 4; ++ks) {
        nA[ks] = *(const bf16x8*)(pA + ks * 512);
        nB[ks] = *(const bf16x8*)(pB + ks * 512);
      }
    }

#pragma unroll
    for (int half = 0; half < 2; ++half) {
      const int c = half ? cB : cA;
      const bool vslot = (2 * pi + half) < nsel;
      f32x4 acc = {};
#pragma unroll
      for (int ks = 0; ks < 4; ++ks) {
        bf16x8 kf = half ? kB[ks] : kA[ks];
        acc = __builtin_amdgcn_mfma_f32_16x16x32_bf16(qfh[ks], kf, acc, 0, 0, 0);
      }
#pragma unroll
      for (int j = 0; j < 4; ++j) {
        const int r = lg * 4 + j;
        const int qrr = q0 + r;
        const int tok = c * 16 + lr;
        u64 sm = (c & 1) ? selO[j] : selE[j];
        bool sel = (sm >> (c >> 1)) & 1ull;
        bool al = vslot && (tok <= qrr) && (sel || (tok > qrr - 128));
        float p = al ? __expf(acc[j] - mxj[j]) : 0.f;
        unsigned short pb = f2bf(p);
        psum[j] += bf2f(pb);
        Pw[pidx2(r, half * 16 + lr)] = pb;
      }
    }
    bf16x8 pa = *(const bf16x8*)&Pw[pidx2(lr, lg * 8)];
#pragma unroll
    for (int dblk = 0; dblk < 8; ++dblk)
      pacc[dblk] = __builtin_amdgcn_mfma_f32_16x16x32_bf16(pa, vf[dblk], pacc[dblk], 0, 0, 0);

#pragma unroll
    for (int ks = 0; ks < 4; ++ks) { kA[ks] = nA[ks]; kB[ks] = nB[ks]; }
  }

#pragma unroll
  for (int j = 0; j < 4; ++j) {
    float s = psum[j];
    s += __shfl_xor(s, 1); s += __shfl_xor(s, 2);
    s += __shfl_xor(s, 4); s += __shfl_xor(s, 8);
    const float rd = 1.0f / s;
    const int r = lg * 4 + j;
#pragma unroll
    for (int dblk = 0; dblk < 8; ++dblk)
      AO[(long)(q0 + r) * 4096 + h * 128 + dblk * 16 + lr] = f2bf(pacc[dblk][j] * rd);
  }
}

// ---------------- launch ----------------
extern "C" void kernel_launch(void* const* d_in, const int* in_sizes, int n_in,
                              void* d_out, int out_size, void* d_ws, size_t ws_size,
                              hipStream_t stream) {
  const float* hidden = (const float*)d_in[0];
  const float* wq = (const float*)d_in[1];
  const float* wk = (const float*)d_in[2];
  const float* wv = (const float*)d_in[3];
  const float* wo = (const float*)d_in[4];
  float* out = (float*)d_out;

  unsigned short* hb_hi = (unsigned short*)d_ws;          // [2048][4096]
  unsigned short* hb_lo = hb_hi + (size_t)2048 * 4096;
  unsigned short* wq_hi = hb_lo + (size_t)2048 * 4096;    // [4096][4096]
  unsigned short* wq_lo = wq_hi + (size_t)4096 * 4096;
  unsigned short* wk_hi = wq_lo + (size_t)4096 * 4096;    // [1024][4096]
  unsigned short* wk_lo = wk_hi + (size_t)1024 * 4096;
  unsigned short* wv_b  = wk_lo + (size_t)1024 * 4096;    // [1024][4096]
  unsigned short* wo_b  = wv_b  + (size_t)1024 * 4096;    // [4096][4096]
  float* Qf = (float*)(wo_b + (size_t)4096 * 4096);       // [2048][4096] fp32
  float* Kf = Qf + (size_t)2048 * 4096;                   // [2048][1024] fp32
  unsigned short* V2 = (unsigned short*)(Kf + (size_t)2048 * 1024);  // frag-major
  // aliases (stream-ordered lifetimes):
  unsigned short* Qhi = wq_hi;        // wq splits dead after QKV GEMM
  unsigned short* Qlo = wq_lo;
  unsigned short* K2h = wk_hi;        // wk splits dead after QKV GEMM
  unsigned short* K2l = wk_lo;
  unsigned short* AO  = hb_hi;        // hidden splits dead after QKV GEMM
  float* ctab = (float*)wv_b;         // wv_b dead after QKV GEMM
  float* stab = ctab + 2048 * 64;
  float* cmaxg = Qf;                  // Qf dead after rope_apply
  u64* selEg = (u64*)Kf;              // Kf dead after rope_apply
  u64* selOg = selEg + 32 * 2048;
  float* mxg = (float*)(selOg + 32 * 2048);

  cvt_all<<<49152, 256, 0, stream>>>(hidden, wq, wk, wv, wo,
                                     hb_hi, hb_lo, wq_hi, wq_lo,
                                     wk_hi, wk_lo, wv_b, wo_b);

  qkv_gemm<<<768, 256, 0, stream>>>(hb_hi, hb_lo, wq_hi, wq_lo,
                                    wk_hi, wk_lo, wv_b, Qf, Kf, V2);

  rope_table<<<512, 256, 0, stream>>>(ctab, stab);
  rope_apply<<<5120, 256, 0, stream>>>(Qf, Kf, ctab, stab, Qhi, Qlo, K2h, K2l);

  cmax_gemm<<<dim3(16, 32), 256, 0, stream>>>(Qhi, Qlo, K2h, K2l, cmaxg);
  select_kernel<<<dim3(32, 32), 256, 0, stream>>>(cmaxg, selEg, selOg, mxg);
  attnB<<<dim3(128, 8), 256, 0, stream>>>(Qhi, K2h, V2, selEg, selOg, mxg, AO);

  gemm_bt<2><<<dim3(32, 16), 256, 0, stream>>>(AO, wo_b, out, 2048, 4096, 4096);
}

// Round 10
// 713.444 us; speedup vs baseline: 1.3514x; 1.0335x over previous
//
#include <hip/hip_runtime.h>
#include <math.h>

typedef __attribute__((ext_vector_type(4))) float f32x4;
typedef __attribute__((ext_vector_type(8))) __bf16 bf16x8;
typedef __attribute__((ext_vector_type(4))) unsigned short us4;
typedef unsigned long long u64;

__device__ __forceinline__ unsigned short f2bf(float f) {
  unsigned int u = __float_as_uint(f);
  u += 0x7fffu + ((u >> 16) & 1u);            // RNE
  return (unsigned short)(u >> 16);
}
__device__ __forceinline__ float bf2f(unsigned short h) {
  return __uint_as_float(((unsigned int)h) << 16);
}

__device__ __forceinline__ void gload16(const void* g, void* l) {
  __builtin_amdgcn_global_load_lds(
      (__attribute__((address_space(1))) void*)g,
      (__attribute__((address_space(3))) void*)l, 16, 0, 0);
}

// ---------------- K2 fragment-major index: K element (s, kvh, d) ----------------
__device__ __forceinline__ long k2idx(int kvh, int s, int d) {
  int ct = s >> 4;
  int lane = (((d & 31) >> 3) << 4) | (s & 15);
  return ((long)(kvh * 128 + ct) * 4 + (d >> 5)) * 512 + lane * 8 + (d & 7);
}

// ---------------- fused fp32 -> bf16 conversions (all 5 inputs, one kernel) ----------------
__device__ __forceinline__ void split1(const float* __restrict__ in,
                                       unsigned short* __restrict__ hi,
                                       unsigned short* __restrict__ lo, int i) {
  float4 v = ((const float4*)in)[i];
  us4 h, l;
  float vv[4] = {v.x, v.y, v.z, v.w};
#pragma unroll
  for (int j = 0; j < 4; ++j) {
    unsigned short hh = f2bf(vv[j]);
    h[j] = hh;
    l[j] = f2bf(vv[j] - bf2f(hh));
  }
  ((us4*)hi)[i] = h;
  ((us4*)lo)[i] = l;
}
__device__ __forceinline__ void plain1(const float* __restrict__ in,
                                       unsigned short* __restrict__ out, int i) {
  float4 v = ((const float4*)in)[i];
  us4 o;
  o[0] = f2bf(v.x); o[1] = f2bf(v.y); o[2] = f2bf(v.z); o[3] = f2bf(v.w);
  ((us4*)out)[i] = o;
}

__global__ __launch_bounds__(256) void cvt_all(const float* __restrict__ hidden,
                                               const float* __restrict__ wq,
                                               const float* __restrict__ wk,
                                               const float* __restrict__ wv,
                                               const float* __restrict__ wo,
                                               unsigned short* __restrict__ hb_hi,
                                               unsigned short* __restrict__ hb_lo,
                                               unsigned short* __restrict__ wq_hi,
                                               unsigned short* __restrict__ wq_lo,
                                               unsigned short* __restrict__ wk_hi,
                                               unsigned short* __restrict__ wk_lo,
                                               unsigned short* __restrict__ wv_b,
                                               unsigned short* __restrict__ wo_b) {
  int i = blockIdx.x * 256 + threadIdx.x;
  if (i < 2097152)       split1(hidden, hb_hi, hb_lo, i);
  else if (i < 6291456)  split1(wq, wq_hi, wq_lo, i - 2097152);
  else if (i < 7340032)  split1(wk, wk_hi, wk_lo, i - 6291456);
  else if (i < 8388608)  plain1(wv, wv_b, i - 7340032);
  else if (i < 12582912) plain1(wo, wo_b, i - 8388608);
}

// ---------------- RoPE angle table (staged in d_out; overwritten by final GEMM) ----------------
__global__ __launch_bounds__(256) void rope_table(float* __restrict__ ctab,
                                                  float* __restrict__ stab) {
  int idx = blockIdx.x * 256 + threadIdx.x;   // 2048*64
  if (idx >= 2048 * 64) return;
  int s = idx >> 6, d = idx & 63;
  float inv = powf(10000.0f, -(float)d * (1.0f / 64.0f));
  float ang = (float)s * inv;
  ctab[idx] = cosf(ang);
  stab[idx] = sinf(ang);
}

// ======== fused QKV projection GEMM + in-epilogue RoPE/split ========
// Outputs go to DEDICATED buffers (no aliasing with weights read by other blocks — round-9 race fix).
__global__ __launch_bounds__(256) void qkv_gemm(const unsigned short* __restrict__ Ahg,
                                                const unsigned short* __restrict__ Alg,
                                                const unsigned short* __restrict__ wq_hi,
                                                const unsigned short* __restrict__ wq_lo,
                                                const unsigned short* __restrict__ wk_hi,
                                                const unsigned short* __restrict__ wk_lo,
                                                const unsigned short* __restrict__ wv_b,
                                                const float* __restrict__ ctab,
                                                const float* __restrict__ stab,
                                                unsigned short* __restrict__ Qh,
                                                unsigned short* __restrict__ Ql,
                                                unsigned short* __restrict__ K2h,
                                                unsigned short* __restrict__ K2l,
                                                unsigned short* __restrict__ V2) {
  __shared__ __align__(16) unsigned short shb[32768];   // 64 KB: staging, then fp32 C-tile
  const int bid = blockIdx.x;
  const int tid = threadIdx.x;
  const int w = tid >> 6, l = tid & 63;
  const int wm = w >> 1, wn = w & 1;
  const int lr = l & 15, lg = l >> 4;
  const int K = 4096;
  const int nt = K >> 5;   // 128

  if (bid >= 128 && bid < 256) {
    // ---------------- V-proj: 1-term bf16, V2 fragment-major store ----------------
    const int b3 = bid - 128;
    const long m0 = (long)(b3 >> 3) * 128, n0 = (long)(b3 & 7) * 128;
    f32x4 acc[4][4] = {};
    const int c0 = w * 128 + l;
    const int c1 = c0 + 64;
    const unsigned short* gA0 = Ahg + (m0 + (c0 >> 2)) * K + (c0 & 3) * 8;
    const unsigned short* gA1 = Ahg + (m0 + (c1 >> 2)) * K + (c1 & 3) * 8;
    const unsigned short* gB0 = wv_b + (n0 + (c0 >> 2)) * K + (c0 & 3) * 8;
    const unsigned short* gB1 = wv_b + (n0 + (c1 >> 2)) * K + (c1 & 3) * 8;

#define STAGE1(t, b)                                         \
  {                                                          \
    long kt = (long)(t) * 32;                                \
    gload16(gA0 + kt, &shb[(b) * 4096 + w * 1024]);          \
    gload16(gA1 + kt, &shb[(b) * 4096 + w * 1024 + 512]);    \
    gload16(gB0 + kt, &shb[16384 + (b) * 4096 + w * 1024]);  \
    gload16(gB1 + kt, &shb[16384 + (b) * 4096 + w * 1024 + 512]); \
  }
    STAGE1(0, 0);
    STAGE1(1, 1);
    for (int t = 0; t < nt; ++t) {
      if (t + 1 < nt) asm volatile("s_waitcnt vmcnt(4)" ::: "memory");
      else            asm volatile("s_waitcnt vmcnt(0)" ::: "memory");
      __builtin_amdgcn_s_barrier();
      __builtin_amdgcn_sched_barrier(0);
      const int b = t & 1;
      bf16x8 af[4], bfr[4];
#pragma unroll
      for (int mi = 0; mi < 4; ++mi)
        af[mi] = *(const bf16x8*)&shb[b * 4096 + (wm * 64 + mi * 16 + lr) * 32 + lg * 8];
#pragma unroll
      for (int ni = 0; ni < 4; ++ni)
        bfr[ni] = *(const bf16x8*)&shb[16384 + b * 4096 + (wn * 64 + ni * 16 + lr) * 32 + lg * 8];
#pragma unroll
      for (int mi = 0; mi < 4; ++mi)
#pragma unroll
        for (int ni = 0; ni < 4; ++ni)
          acc[mi][ni] = __builtin_amdgcn_mfma_f32_16x16x32_bf16(af[mi], bfr[ni], acc[mi][ni], 0, 0, 0);
      __builtin_amdgcn_sched_barrier(0);
      __builtin_amdgcn_s_barrier();
      __builtin_amdgcn_sched_barrier(0);
      if (t + 2 < nt) STAGE1(t + 2, b);
    }
#undef STAGE1
#pragma unroll
    for (int mi = 0; mi < 4; ++mi)
#pragma unroll
      for (int ni = 0; ni < 4; ++ni)
#pragma unroll
        for (int j = 0; j < 4; ++j) {
          long r = m0 + wm * 64 + mi * 16 + lg * 4 + j;
          long cc = n0 + wn * 64 + ni * 16 + lr;
          int kvh = (int)(cc >> 7), d = (int)(cc & 127);
          int c = (int)(r >> 4), t2 = (int)(r & 15);
          long idx = ((long)(kvh * 128 + c) * 8 + (d >> 4)) * 256 + ((t2 >> 3) * 16 + (d & 15)) * 8 + (t2 & 7);
          V2[idx] = f2bf(acc[mi][ni][j]);
        }
    return;
  }

  // ---------------- Q-proj / K-proj: 3-term split GEMM + rope epilogue ----------------
  const unsigned short *Bh, *Bl;
  long m0, n0;
  bool isQ;
  if (bid < 128) {
    m0 = (long)(bid >> 3) * 128; n0 = (long)(bid & 7) * 128;   // xcd = n (wk panel hot per-XCD)
    Bh = wk_hi; Bl = wk_lo; isQ = false;
  } else {
    const int q = bid - 256;
    const int ord = q >> 3;                                    // xcd = q&7 -> 4 n-panels per XCD
    const int n = (q & 7) * 4 + (ord >> 4);
    const int m = ord & 15;
    m0 = (long)m * 128; n0 = (long)n * 128;
    Bh = wq_hi; Bl = wq_lo; isQ = true;
  }

  f32x4 acc[4][4] = {};
  const int c0 = w * 128 + l;
  const int c1 = c0 + 64;
  const long oA0 = (m0 + (c0 >> 2)) * K + (c0 & 3) * 8;
  const long oA1 = (m0 + (c1 >> 2)) * K + (c1 & 3) * 8;
  const long oB0 = (n0 + (c0 >> 2)) * K + (c0 & 3) * 8;
  const long oB1 = (n0 + (c1 >> 2)) * K + (c1 & 3) * 8;

#define STAGE3(t, b)                                               \
  {                                                                \
    long kt = (long)(t) * 32;                                      \
    gload16(Ahg + oA0 + kt, &shb[(b) * 4096 + w * 1024]);          \
    gload16(Ahg + oA1 + kt, &shb[(b) * 4096 + w * 1024 + 512]);    \
    gload16(Alg + oA0 + kt, &shb[8192 + (b) * 4096 + w * 1024]);   \
    gload16(Alg + oA1 + kt, &shb[8192 + (b) * 4096 + w * 1024 + 512]); \
    gload16(Bh + oB0 + kt, &shb[16384 + (b) * 4096 + w * 1024]);   \
    gload16(Bh + oB1 + kt, &shb[16384 + (b) * 4096 + w * 1024 + 512]); \
    gload16(Bl + oB0 + kt, &shb[24576 + (b) * 4096 + w * 1024]);   \
    gload16(Bl + oB1 + kt, &shb[24576 + (b) * 4096 + w * 1024 + 512]); \
  }
  STAGE3(0, 0);
  STAGE3(1, 1);
  for (int t = 0; t < nt; ++t) {
    if (t + 1 < nt) asm volatile("s_waitcnt vmcnt(8)" ::: "memory");
    else            asm volatile("s_waitcnt vmcnt(0)" ::: "memory");
    __builtin_amdgcn_s_barrier();
    __builtin_amdgcn_sched_barrier(0);
    const int b = t & 1;
    bf16x8 afh[4], afl[4], bfh[4], bfl[4];
#pragma unroll
    for (int mi = 0; mi < 4; ++mi) {
      afh[mi] = *(const bf16x8*)&shb[b * 4096 + (wm * 64 + mi * 16 + lr) * 32 + lg * 8];
      afl[mi] = *(const bf16x8*)&shb[8192 + b * 4096 + (wm * 64 + mi * 16 + lr) * 32 + lg * 8];
    }
#pragma unroll
    for (int ni = 0; ni < 4; ++ni) {
      bfh[ni] = *(const bf16x8*)&shb[16384 + b * 4096 + (wn * 64 + ni * 16 + lr) * 32 + lg * 8];
      bfl[ni] = *(const bf16x8*)&shb[24576 + b * 4096 + (wn * 64 + ni * 16 + lr) * 32 + lg * 8];
    }
#pragma unroll
    for (int mi = 0; mi < 4; ++mi)
#pragma unroll
      for (int ni = 0; ni < 4; ++ni) {
        acc[mi][ni] = __builtin_amdgcn_mfma_f32_16x16x32_bf16(afh[mi], bfh[ni], acc[mi][ni], 0, 0, 0);
        acc[mi][ni] = __builtin_amdgcn_mfma_f32_16x16x32_bf16(afl[mi], bfh[ni], acc[mi][ni], 0, 0, 0);
        acc[mi][ni] = __builtin_amdgcn_mfma_f32_16x16x32_bf16(afh[mi], bfl[ni], acc[mi][ni], 0, 0, 0);
      }
    __builtin_amdgcn_sched_barrier(0);
    __builtin_amdgcn_s_barrier();
    __builtin_amdgcn_sched_barrier(0);
    if (t + 2 < nt) STAGE3(t + 2, b);
  }
#undef STAGE3

  // ---- epilogue: C tile -> LDS fp32, then rope+split (bit-identical to old rope_apply) ----
  __syncthreads();
  float* Cls = (float*)shb;                    // 128 x 128 fp32 = 64 KB
#pragma unroll
  for (int mi = 0; mi < 4; ++mi)
#pragma unroll
    for (int ni = 0; ni < 4; ++ni)
#pragma unroll
      for (int j = 0; j < 4; ++j)
        Cls[(wm * 64 + mi * 16 + lg * 4 + j) * 128 + (wn * 64 + ni * 16 + lr)] = acc[mi][ni][j];
  __syncthreads();

  const int hqk = (int)(n0 >> 7);              // head (Q) or kv-head (K)
  const int r0l = tid >> 3;                    // 0..31
  const int d0 = (tid & 7) * 8;                // 0..56
  const float scale = isQ ? 0.08838834764831845f : 1.0f;
#pragma unroll
  for (int k = 0; k < 4; ++k) {
    const int r = r0l + 32 * k;
    const long s = m0 + r;
    float X1[8], X2[8], CC[8], SS[8];
    {
      f32x4 a = *(const f32x4*)&Cls[r * 128 + d0];
      f32x4 b = *(const f32x4*)&Cls[r * 128 + d0 + 4];
      f32x4 c = *(const f32x4*)&Cls[r * 128 + 64 + d0];
      f32x4 d = *(const f32x4*)&Cls[r * 128 + 64 + d0 + 4];
      f32x4 e = *(const f32x4*)&ctab[s * 64 + d0];
      f32x4 f = *(const f32x4*)&ctab[s * 64 + d0 + 4];
      f32x4 g = *(const f32x4*)&stab[s * 64 + d0];
      f32x4 h = *(const f32x4*)&stab[s * 64 + d0 + 4];
#pragma unroll
      for (int j = 0; j < 4; ++j) {
        X1[j] = a[j]; X1[j + 4] = b[j];
        X2[j] = c[j]; X2[j + 4] = d[j];
        CC[j] = e[j]; CC[j + 4] = f[j];
        SS[j] = g[j]; SS[j + 4] = h[j];
      }
    }
    us4 H1[2], L1[2], H2[2], L2[2];
#pragma unroll
    for (int j = 0; j < 8; ++j) {
      float y1 = (X1[j] * CC[j] - X2[j] * SS[j]) * scale;
      float y2 = (X2[j] * CC[j] + X1[j] * SS[j]) * scale;
      unsigned short h1 = f2bf(y1), h2 = f2bf(y2);
      H1[j >> 2][j & 3] = h1; L1[j >> 2][j & 3] = f2bf(y1 - bf2f(h1));
      H2[j >> 2][j & 3] = h2; L2[j >> 2][j & 3] = f2bf(y2 - bf2f(h2));
    }
    if (isQ) {
      long row = s * 4096 + hqk * 128;
      *(us4*)&Qh[row + d0] = H1[0];      *(us4*)&Qh[row + d0 + 4] = H1[1];
      *(us4*)&Ql[row + d0] = L1[0];      *(us4*)&Ql[row + d0 + 4] = L1[1];
      *(us4*)&Qh[row + 64 + d0] = H2[0]; *(us4*)&Qh[row + 64 + d0 + 4] = H2[1];
      *(us4*)&Ql[row + 64 + d0] = L2[0]; *(us4*)&Ql[row + 64 + d0 + 4] = L2[1];
    } else {
      long i1 = k2idx(hqk, (int)s, d0);
      long i2 = k2idx(hqk, (int)s, d0 + 64);
      *(us4*)&K2h[i1] = H1[0]; *(us4*)&K2h[i1 + 4] = H1[1];
      *(us4*)&K2l[i1] = L1[0]; *(us4*)&K2l[i1 + 4] = L1[1];
      *(us4*)&K2h[i2] = H2[0]; *(us4*)&K2h[i2 + 4] = H2[1];
      *(us4*)&K2l[i2] = L2[0]; *(us4*)&K2l[i2 + 4] = L2[1];
    }
  }
}

// ---------------- GEMM: C = A * B^T (O-proj), counted-vmcnt double-buffered ----------------
__global__ __launch_bounds__(256) void gemm_bt(const unsigned short* __restrict__ A,
                                               const unsigned short* __restrict__ B,
                                               float* __restrict__ C,
                                               int M, int N, int K) {
  __shared__ __align__(16) unsigned short As[2][4096];
  __shared__ __align__(16) unsigned short Bs[2][4096];
  const int tid = threadIdx.x;
  const int w = tid >> 6, l = tid & 63;
  const int wm = w >> 1, wn = w & 1;
  const int lr = l & 15, lg = l >> 4;
  const long m0 = (long)blockIdx.y * 128, n0 = (long)blockIdx.x * 128;

  f32x4 acc[4][4] = {};

  const int c0 = w * 128 + l;
  const int c1 = c0 + 64;
  const unsigned short* gA0 = A + (m0 + (c0 >> 2)) * K + (c0 & 3) * 8;
  const unsigned short* gA1 = A + (m0 + (c1 >> 2)) * K + (c1 & 3) * 8;
  const unsigned short* gB0 = B + (n0 + (c0 >> 2)) * K + (c0 & 3) * 8;
  const unsigned short* gB1 = B + (n0 + (c1 >> 2)) * K + (c1 & 3) * 8;

#define STAGE1(t, b)                                   \
  {                                                    \
    long kt = (long)(t) * 32;                          \
    gload16(gA0 + kt, &As[b][w * 1024]);               \
    gload16(gA1 + kt, &As[b][w * 1024 + 512]);         \
    gload16(gB0 + kt, &Bs[b][w * 1024]);               \
    gload16(gB1 + kt, &Bs[b][w * 1024 + 512]);         \
  }

  const int nt = K >> 5;
  STAGE1(0, 0);
  if (nt > 1) STAGE1(1, 1);

  for (int t = 0; t < nt; ++t) {
    if (t + 1 < nt) asm volatile("s_waitcnt vmcnt(4)" ::: "memory");
    else            asm volatile("s_waitcnt vmcnt(0)" ::: "memory");
    __builtin_amdgcn_s_barrier();
    __builtin_amdgcn_sched_barrier(0);
    const int b = t & 1;
    bf16x8 af[4], bfr[4];
#pragma unroll
    for (int mi = 0; mi < 4; ++mi)
      af[mi] = *(const bf16x8*)&As[b][(wm * 64 + mi * 16 + lr) * 32 + lg * 8];
#pragma unroll
    for (int ni = 0; ni < 4; ++ni)
      bfr[ni] = *(const bf16x8*)&Bs[b][(wn * 64 + ni * 16 + lr) * 32 + lg * 8];
#pragma unroll
    for (int mi = 0; mi < 4; ++mi)
#pragma unroll
      for (int ni = 0; ni < 4; ++ni)
        acc[mi][ni] = __builtin_amdgcn_mfma_f32_16x16x32_bf16(af[mi], bfr[ni], acc[mi][ni], 0, 0, 0);
    __builtin_amdgcn_sched_barrier(0);
    __builtin_amdgcn_s_barrier();
    __builtin_amdgcn_sched_barrier(0);
    if (t + 2 < nt) STAGE1(t + 2, b);
  }
#undef STAGE1

#pragma unroll
  for (int mi = 0; mi < 4; ++mi)
#pragma unroll
    for (int ni = 0; ni < 4; ++ni)
#pragma unroll
      for (int j = 0; j < 4; ++j) {
        long r = m0 + wm * 64 + mi * 16 + lg * 4 + j;
        long cc = n0 + wn * 64 + ni * 16 + lr;
        C[r * N + cc] = acc[mi][ni][j];
      }
}

// ======== K1: cmax GEMM, 4-deep counted-vmcnt pipeline. ========
__global__ __launch_bounds__(256, 2) void cmax_gemm(const unsigned short* __restrict__ Qh,
                                                    const unsigned short* __restrict__ Ql,
                                                    const unsigned short* __restrict__ K2h,
                                                    const unsigned short* __restrict__ K2l,
                                                    float* __restrict__ cmaxg) {
  __shared__ __align__(16) unsigned short Ksh[4][4096];  // 4 x 8KB hi (32-tok panel)
  __shared__ __align__(16) unsigned short Ksl[4][4096];  // 4 x 8KB lo
  const int qp = 15 - (int)blockIdx.x;                   // heavy panels first
  const int h = blockIdx.y;
  const int kvh = h >> 2;
  const int q0 = qp * 128;
  const int tid = threadIdx.x;
  const int w = tid >> 6, l = tid & 63;
  const int lr = l & 15, lg = l >> 4;
  const int npan = 4 * (qp + 1);
  const float NEGINF = -__builtin_inff();

  bf16x8 qfh[2][4], qfl[2][4];
#pragma unroll
  for (int rg = 0; rg < 2; ++rg) {
    const unsigned short* qph = Qh + (long)(q0 + w * 32 + rg * 16 + lr) * 4096 + h * 128 + lg * 8;
    const unsigned short* qpl = Ql + (long)(q0 + w * 32 + rg * 16 + lr) * 4096 + h * 128 + lg * 8;
#pragma unroll
    for (int ks = 0; ks < 4; ++ks) {
      qfh[rg][ks] = *(const bf16x8*)(qph + ks * 32);
      qfl[rg][ks] = *(const bf16x8*)(qpl + ks * 32);
    }
  }

  const unsigned short* kbh = K2h + (long)kvh * 128 * 2048;
  const unsigned short* kbl = K2l + (long)kvh * 128 * 2048;

#define STAGE(kp, b)                                                       \
  {                                                                        \
    long off = (long)(kp) * 4096;                                          \
    _Pragma("unroll")                                                      \
    for (int i = 0; i < 2; ++i) {                                          \
      int cu = w * 128 + i * 64;                                           \
      gload16(kbh + off + (cu + l) * 8, &Ksh[b][cu * 8]);                  \
      gload16(kbl + off + (cu + l) * 8, &Ksl[b][cu * 8]);                  \
    }                                                                      \
  }

  STAGE(0, 0);
  if (1 < npan) STAGE(1, 1);
  if (2 < npan) STAGE(2, 2);

  for (int kp = 0; kp < npan; ++kp) {
    {
      int ahead = npan - 1 - kp; if (ahead > 2) ahead = 2;
      int st = kp; if (st > 3) st = 3;
      int tgt = 4 * ahead + 4 * st;
      if (tgt >= 20)      asm volatile("s_waitcnt vmcnt(20)" ::: "memory");
      else if (tgt >= 16) asm volatile("s_waitcnt vmcnt(16)" ::: "memory");
      else if (tgt >= 12) asm volatile("s_waitcnt vmcnt(12)" ::: "memory");
      else if (tgt >= 8)  asm volatile("s_waitcnt vmcnt(8)" ::: "memory");
      else                asm volatile("s_waitcnt vmcnt(0)" ::: "memory");
    }
    __builtin_amdgcn_s_barrier();
    __builtin_amdgcn_sched_barrier(0);
    if (kp + 3 < npan) STAGE(kp + 3, (kp + 3) & 3);
    const int b = kp & 3;
#pragma unroll
    for (int c2 = 0; c2 < 2; ++c2) {
      const int ct = kp * 2 + c2;
      bf16x8 kh[4], kl2[4];
#pragma unroll
      for (int ks = 0; ks < 4; ++ks) {
        kh[ks]  = *(const bf16x8*)&Ksh[b][(c2 * 4 + ks) * 512 + l * 8];
        kl2[ks] = *(const bf16x8*)&Ksl[b][(c2 * 4 + ks) * 512 + l * 8];
      }
#pragma unroll
      for (int rg = 0; rg < 2; ++rg) {
        f32x4 acc = {};
#pragma unroll
        for (int ks = 0; ks < 4; ++ks) {
          acc = __builtin_amdgcn_mfma_f32_16x16x32_bf16(kh[ks], qfh[rg][ks], acc, 0, 0, 0);
          acc = __builtin_amdgcn_mfma_f32_16x16x32_bf16(kh[ks], qfl[rg][ks], acc, 0, 0, 0);
          acc = __builtin_amdgcn_mfma_f32_16x16x32_bf16(kl2[ks], qfh[rg][ks], acc, 0, 0, 0);
        }
        const int rbase = q0 + w * 32 + rg * 16;
        float m;
        if (ct * 16 + 15 <= rbase) {
          m = fmaxf(fmaxf(acc[0], acc[1]), fmaxf(acc[2], acc[3]));
        } else {
          m = NEGINF;
#pragma unroll
          for (int j = 0; j < 4; ++j) {
            int tok = ct * 16 + lg * 4 + j;
            if (tok <= rbase + lr) m = fmaxf(m, acc[j]);
          }
        }
        m = fmaxf(m, __shfl_xor(m, 16));
        m = fmaxf(m, __shfl_xor(m, 32));
        if (l < 16) cmaxg[(long)(h * 128 + ct) * 2048 + rbase + l] = m;
      }
    }
  }
#undef STAGE
}

// ======== K2: per-row top-8 selection. block = (64-row group, head). ========
__global__ __launch_bounds__(256) void select_kernel(const float* __restrict__ cmaxg,
                                                     u64* __restrict__ selEg,
                                                     u64* __restrict__ selOg,
                                                     float* __restrict__ mxg) {
  __shared__ float Lc[128 * 65];                  // [ct][row], padded
  const int r0 = (int)blockIdx.x * 64;
  const int h = blockIdx.y;
  const int tid = threadIdx.x;
  const int w = tid >> 6, l = tid & 63;
  const float NEGINF = -__builtin_inff();

  for (int i = tid; i < 128 * 16; i += 256) {
    int ct = i >> 4, rq = (i & 15) * 4;
    float4 v = *(const float4*)&cmaxg[(long)(h * 128 + ct) * 2048 + r0 + rq];
    Lc[ct * 65 + rq]     = v.x;
    Lc[ct * 65 + rq + 1] = v.y;
    Lc[ct * 65 + rq + 2] = v.z;
    Lc[ct * 65 + rq + 3] = v.w;
  }
  __syncthreads();

  const int c0 = 2 * l, c1 = 2 * l + 1;
#pragma unroll 1
  for (int rs = 0; rs < 16; ++rs) {
    const int rloc = w * 16 + rs;
    const int qr = r0 + rloc;
    const int nctr = (qr >> 4) + 1;
    float v0 = (c0 < nctr) ? Lc[c0 * 65 + rloc] : NEGINF;
    float v1 = (c1 < nctr) ? Lc[c1 * 65 + rloc] : NEGINF;
    const float o0 = v0, o1 = v1;
    float T = NEGINF;
    for (int it = 0; it < 8; ++it) {
      float m = fmaxf(v0, v1);
#pragma unroll
      for (int o = 1; o < 64; o <<= 1) m = fmaxf(m, __shfl_xor(m, o));
      u64 bal = __ballot((v0 == m) || (v1 == m));
      int first = __ffsll(bal) - 1;
      if (l == first) { if (v0 == m) v0 = NEGINF; else v1 = NEGINF; }
      T = m;
    }
    bool okc0 = (c0 < nctr) && ((c0 < 8) || (o0 >= T));
    bool okc1 = (c1 < nctr) && ((c1 < 8) || (o1 >= T));
    u64 bE = __ballot(okc0);
    u64 bO = __ballot(okc1);
    bool al0 = (c0 < nctr) && (okc0 || (c0 * 16 + 15 > qr - 128));
    bool al1 = (c1 < nctr) && (okc1 || (c1 * 16 + 15 > qr - 128));
    float mv = fmaxf(al0 ? o0 : NEGINF, al1 ? o1 : NEGINF);
#pragma unroll
    for (int o = 1; o < 64; o <<= 1) mv = fmaxf(mv, __shfl_xor(mv, o));
    if (l == 0) {
      selEg[h * 2048 + qr] = bE;
      selOg[h * 2048 + qr] = bO;
      mxg[h * 2048 + qr] = mv;
    }
  }
}

// ---------------- P LDS swizzled index (per-wave slice): row, tok32 ----------------
__device__ __forceinline__ int pidx2(int r, int t) {
  return r * 32 + ((((t >> 3) ^ (r & 3)) << 3) | (t & 7));
}

// ======== K3: phase B — recompute selected chunks, exp, PV; K prefetched 1 pair ahead. ========
__global__ __launch_bounds__(256) void attnB(const unsigned short* __restrict__ Qh,
                                             const unsigned short* __restrict__ K2h,
                                             const unsigned short* __restrict__ V2,
                                             const u64* __restrict__ selEg,
                                             const u64* __restrict__ selOg,
                                             const float* __restrict__ mxg,
                                             unsigned short* __restrict__ AO) {
  __shared__ __align__(16) unsigned short Pls[4][512];
  __shared__ int clistS[4][128];

  const int qb = (int)gridDim.x - 1 - (int)blockIdx.x;   // heavy blocks first
  const int kvh = blockIdx.y;
  const int q0 = qb * 16;
  const int nct = qb + 1;
  const int tid = threadIdx.x;
  const int w = tid >> 6, l = tid & 63;
  const int lr = l & 15, lg = l >> 4;
  const int h = kvh * 4 + w;

  bf16x8 qfh[4];
  {
    const unsigned short* qph = Qh + (long)(q0 + lr) * 4096 + h * 128 + lg * 8;
#pragma unroll
    for (int ks = 0; ks < 4; ++ks) qfh[ks] = *(const bf16x8*)(qph + ks * 32);
  }

  u64 myE = selEg[h * 2048 + q0 + lr];
  u64 myO = selOg[h * 2048 + q0 + lr];
  float mymx = mxg[h * 2048 + q0 + lr];

  u64 uE = myE, uO = myO;
#pragma unroll
  for (int o = 1; o < 16; o <<= 1) {
    uE |= __shfl_xor(uE, o);
    uO |= __shfl_xor(uO, o);
  }
  float mxj[4];
  u64 selE[4], selO[4];
#pragma unroll
  for (int j = 0; j < 4; ++j) {
    mxj[j] = __shfl(mymx, lg * 4 + j);
    selE[j] = __shfl(myE, lg * 4 + j);
    selO[j] = __shfl(myO, lg * 4 + j);
  }

  unsigned short* Pw = Pls[w];
  int* cl = clistS[w];

  const int c0 = 2 * l, c1 = 2 * l + 1;
  bool s0ok = (c0 < nct) && (((uE >> l) & 1ull) || (c0 >= qb - 7));
  bool s1ok = (c1 < nct) && (((uO >> l) & 1ull) || (c1 >= qb - 7));
  u64 bA = __ballot(s0ok);
  u64 bB = __ballot(s1ok);
  const int cntA = __popcll(bA);
  const int nsel = cntA + __popcll(bB);
  if (s0ok) cl[__popcll(bA & ((1ull << l) - 1ull))] = c0;
  if (s1ok) cl[cntA + __popcll(bB & ((1ull << l) - 1ull))] = c1;

  const unsigned short* kbh = K2h + (long)kvh * 128 * 2048;

  f32x4 pacc[8] = {};
  float psum[4] = {0.f, 0.f, 0.f, 0.f};
  const int np = (nsel + 1) >> 1;

  bf16x8 kA[4], kB[4];
  {
    const int cA0 = cl[0];
    const int cB0 = (1 < nsel) ? cl[1] : cA0;
    const unsigned short* pA = kbh + (long)cA0 * 2048 + l * 8;
    const unsigned short* pB = kbh + (long)cB0 * 2048 + l * 8;
#pragma unroll
    for (int ks = 0; ks < 4; ++ks) {
      kA[ks] = *(const bf16x8*)(pA + ks * 512);
      kB[ks] = *(const bf16x8*)(pB + ks * 512);
    }
  }

  for (int pi = 0; pi < np; ++pi) {
    const int cA = cl[2 * pi];
    const int iB = 2 * pi + 1;
    const int cB = (iB < nsel) ? cl[iB] : cA;

    const int csel = (lg < 2) ? cA : cB;
    const unsigned short* vp = V2 + (long)(kvh * 128 + csel) * 2048 + ((lg & 1) * 16 + lr) * 8;
    bf16x8 vf[8];
#pragma unroll
    for (int dblk = 0; dblk < 8; ++dblk) vf[dblk] = *(const bf16x8*)(vp + dblk * 256);

    bf16x8 nA[4], nB[4];
    {
      const int pin = (pi + 1 < np) ? pi + 1 : pi;
      const int cA1 = cl[2 * pin];
      const int iB1 = 2 * pin + 1;
      const int cB1 = (iB1 < nsel) ? cl[iB1] : cA1;
      const unsigned short* pA = kbh + (long)cA1 * 2048 + l * 8;
      const unsigned short* pB = kbh + (long)cB1 * 2048 + l * 8;
#pragma unroll
      for (int ks = 0; ks < 4; ++ks) {
        nA[ks] = *(const bf16x8*)(pA + ks * 512);
        nB[ks] = *(const bf16x8*)(pB + ks * 512);
      }
    }

#pragma unroll
    for (int half = 0; half < 2; ++half) {
      const int c = half ? cB : cA;
      const bool vslot = (2 * pi + half) < nsel;
      f32x4 acc = {};
#pragma unroll
      for (int ks = 0; ks < 4; ++ks) {
        bf16x8 kf = half ? kB[ks] : kA[ks];
        acc = __builtin_amdgcn_mfma_f32_16x16x32_bf16(qfh[ks], kf, acc, 0, 0, 0);
      }
#pragma unroll
      for (int j = 0; j < 4; ++j) {
        const int r = lg * 4 + j;
        const int qrr = q0 + r;
        const int tok = c * 16 + lr;
        u64 sm = (c & 1) ? selO[j] : selE[j];
        bool sel = (sm >> (c >> 1)) & 1ull;
        bool al = vslot && (tok <= qrr) && (sel || (tok > qrr - 128));
        float p = al ? __expf(acc[j] - mxj[j]) : 0.f;
        unsigned short pb = f2bf(p);
        psum[j] += bf2f(pb);
        Pw[pidx2(r, half * 16 + lr)] = pb;
      }
    }
    bf16x8 pa = *(const bf16x8*)&Pw[pidx2(lr, lg * 8)];
#pragma unroll
    for (int dblk = 0; dblk < 8; ++dblk)
      pacc[dblk] = __builtin_amdgcn_mfma_f32_16x16x32_bf16(pa, vf[dblk], pacc[dblk], 0, 0, 0);

#pragma unroll
    for (int ks = 0; ks < 4; ++ks) { kA[ks] = nA[ks]; kB[ks] = nB[ks]; }
  }

#pragma unroll
  for (int j = 0; j < 4; ++j) {
    float s = psum[j];
    s += __shfl_xor(s, 1); s += __shfl_xor(s, 2);
    s += __shfl_xor(s, 4); s += __shfl_xor(s, 8);
    const float rd = 1.0f / s;
    const int r = lg * 4 + j;
#pragma unroll
    for (int dblk = 0; dblk < 8; ++dblk)
      AO[(long)(q0 + r) * 4096 + h * 128 + dblk * 16 + lr] = f2bf(pacc[dblk][j] * rd);
  }
}

// ---------------- launch ----------------
extern "C" void kernel_launch(void* const* d_in, const int* in_sizes, int n_in,
                              void* d_out, int out_size, void* d_ws, size_t ws_size,
                              hipStream_t stream) {
  const float* hidden = (const float*)d_in[0];
  const float* wq = (const float*)d_in[1];
  const float* wk = (const float*)d_in[2];
  const float* wv = (const float*)d_in[3];
  const float* wo = (const float*)d_in[4];
  float* out = (float*)d_out;

  unsigned short* hb_hi = (unsigned short*)d_ws;          // [2048][4096]
  unsigned short* hb_lo = hb_hi + (size_t)2048 * 4096;
  unsigned short* wq_hi = hb_lo + (size_t)2048 * 4096;    // [4096][4096]
  unsigned short* wq_lo = wq_hi + (size_t)4096 * 4096;
  unsigned short* wk_hi = wq_lo + (size_t)4096 * 4096;    // [1024][4096]
  unsigned short* wk_lo = wk_hi + (size_t)1024 * 4096;
  unsigned short* wv_b  = wk_lo + (size_t)1024 * 4096;    // [1024][4096]
  unsigned short* wo_b  = wv_b  + (size_t)1024 * 4096;    // [4096][4096]
  // dedicated output region (race fix): Qh/Ql in old-Qf (32 MB), K2h/K2l/V2 in old-Kf+V2 (12 MB)
  unsigned short* Qhi = wo_b + (size_t)4096 * 4096;       // [2048][4096] bf16
  unsigned short* Qlo = Qhi + (size_t)2048 * 4096;
  unsigned short* K2h = Qlo + (size_t)2048 * 4096;        // frag-major, 2M elems
  unsigned short* K2l = K2h + (size_t)2048 * 1024;
  unsigned short* V2  = K2l + (size_t)2048 * 1024;        // frag-major, 2M elems
  // aliases (stream-ordered lifetimes):
  unsigned short* AO = hb_hi;         // hidden splits dead after QKV GEMM
  float* cmaxg = (float*)wq_hi;       // wq splits dead after QKV GEMM (33.5 MB <= 64 MB)
  u64* selEg = (u64*)wk_hi;           // wk splits dead after QKV GEMM
  u64* selOg = selEg + 32 * 2048;
  float* mxg = (float*)(selOg + 32 * 2048);
  float* ctab = out;                  // staged in d_out; fully overwritten by final GEMM
  float* stab = ctab + 2048 * 64;

  cvt_all<<<49152, 256, 0, stream>>>(hidden, wq, wk, wv, wo,
                                     hb_hi, hb_lo, wq_hi, wq_lo,
                                     wk_hi, wk_lo, wv_b, wo_b);
  rope_table<<<512, 256, 0, stream>>>(ctab, stab);

  qkv_gemm<<<768, 256, 0, stream>>>(hb_hi, hb_lo, wq_hi, wq_lo,
                                    wk_hi, wk_lo, wv_b, ctab, stab,
                                    Qhi, Qlo, K2h, K2l, V2);

  cmax_gemm<<<dim3(16, 32), 256, 0, stream>>>(Qhi, Qlo, K2h, K2l, cmaxg);
  select_kernel<<<dim3(32, 32), 256, 0, stream>>>(cmaxg, selEg, selOg, mxg);
  attnB<<<dim3(128, 8), 256, 0, stream>>>(Qhi, K2h, V2, selEg, selOg, mxg, AO);

  gemm_bt<<<dim3(32, 16), 256, 0, stream>>>(AO, wo_b, out, 2048, 4096, 4096);
}